// Round 4
// baseline (2169.915 us; speedup 1.0000x reference)
//
#include <hip/hip_runtime.h>

typedef __attribute__((ext_vector_type(8))) _Float16 f16x8;
typedef __attribute__((ext_vector_type(4))) float f32x4;

#define NN   50000
#define EE   300000
#define TWOE 600000
#define TWOQ 200000
#define QCH  12500

// ---- workspace layout (bytes), total ~184.1 MB ----
static constexpr size_t O_XH   = 0;           // xh f16 [N,256]; later AGGh f16 [N,288]
static constexpr size_t O_XHAT = 28800000;    // f16 [N,288]
static constexpr size_t O_AGG  = 57600000;    // f32 [N,288]
static constexpr size_t O_OPRE = 115200000;   // f32 [N,256]
static constexpr size_t O_CM   = 166400000;   // f16 [QCH,288]
static constexpr size_t O_YH   = 173600000;   // f16 [QCH,288]
static constexpr size_t O_FR   = 180800000;   // f16 [288,256] rfft rows
static constexpr size_t O_FI2  = O_FR   + 147456;  // f16 [288,256] irfft (freq-major)
static constexpr size_t O_T1   = O_FI2  + 147456;  // f16 [288,256]
static constexpr size_t O_G    = O_T1   + 147456;  // f16 [288,288]
static constexpr size_t O_WB   = O_G    + 165888;  // f16 [256,832]
static constexpr size_t O_WQN  = O_WB   + 425984;  // f16 [256,256] w_q natural
static constexpr size_t O_WINT = O_WQN  + 131072;  // f16 [256,256] w_in^T
static constexpr size_t O_WOUT = O_WINT + 131072;  // f16 [256,256] w_out^T
static constexpr size_t O_RAL16= O_WOUT + 131072;  // f16 [501,256]
static constexpr size_t O_RAL32= O_RAL16+ 256512;  // f32 [501,256]
static constexpr size_t O_RHAT = O_RAL32+ 513024;  // f16 [501,288]
static constexpr size_t O_DEG  = O_RHAT + 288576;  // int [2,N]
static constexpr size_t O_DINV = O_DEG  + 400000;  // f32 [2,N]
static constexpr size_t O_BNS  = O_DINV + 400000;  // f32 [1024]
static constexpr size_t WS_NEED= O_BNS  + 4096;

__device__ __forceinline__ float sanit(float v){
  v = (v == v) ? v : 0.f;
  return fminf(60000.f, fmaxf(-60000.f, v));
}
__device__ __forceinline__ _Float16 sat16(float v){ return (_Float16)sanit(v); }
__device__ __forceinline__ int iclamp(int v, int lo, int hi){
  return v < lo ? lo : (v > hi ? hi : v);
}
__device__ __forceinline__ void atomAddF(float* p, float v){
  __hip_atomic_fetch_add(p, v, __ATOMIC_RELAXED, __HIP_MEMORY_SCOPE_AGENT);
}
union HU { unsigned int u; _Float16 h[2]; };

// FR[f][t]: f=2m -> cos(2pi m t/256), f=2m+1 -> -sin; rows 258..287 zero.
// FI2[k][j]: irfft coeff, freq-comp k, time j.
__global__ void k_gen_dft(_Float16* __restrict__ FR, _Float16* __restrict__ FI2){
  int t = blockIdx.x*256 + threadIdx.x;
  if (t >= 288*256) return;
  const float step = 0.024543692606170259f; // 2*pi/256
  {
    int f = t >> 8, tt = t & 255;
    float v = 0.f;
    if (f < 258){
      int m = f >> 1;
      float ang = (float)((tt*m) & 255) * step;
      v = (f & 1) ? -sinf(ang) : cosf(ang);
    }
    FR[t] = (_Float16)v;
  }
  {
    int k = t >> 8, j = t & 255;
    float v = 0.f;
    if (k < 258){
      int m = k >> 1;
      float w = (m==0 || m==128) ? (1.f/256.f) : (2.f/256.f);
      float ang = (float)((j*m) & 255) * step;
      v = (k & 1) ? -w*sinf(ang) : w*cosf(ang);
    }
    FI2[t] = (_Float16)v;
  }
}

__global__ void k_gen_misc(const float* __restrict__ w_in, const float* __restrict__ w_out,
                           const float* __restrict__ w_q, const float* __restrict__ rel_embed,
                           const float* __restrict__ loop_rel,
                           _Float16* __restrict__ wqn, _Float16* __restrict__ wint,
                           _Float16* __restrict__ woutt,
                           float* __restrict__ ral32, _Float16* __restrict__ ral16){
  int t = blockIdx.x*256 + threadIdx.x;
  if (t >= 501*256) return;
  if (t < 65536){
    int j = t >> 8, n = t & 255;
    wqn[t] = sat16(w_q[t]);
    wint[n*256 + j]  = sat16(w_in[t]);
    woutt[n*256 + j] = sat16(w_out[t]);
  }
  float rv = (t < 128000) ? rel_embed[t] : loop_rel[t - 128000];
  rv = sanit(rv);
  ral32[t] = rv; ral16[t] = (_Float16)rv;
}

// WB[n][576+j] = sum_m loop_rel[(j+m)%256] * w_loop[m][n]
__global__ void k_gen_bw(const float* __restrict__ loop_rel, const float* __restrict__ w_loop,
                         _Float16* __restrict__ WB){
  int t = blockIdx.x*256 + threadIdx.x;
  if (t >= 65536) return;
  int j = t >> 8, n = t & 255;
  float acc = 0.f;
  for (int m = 0; m < 256; ++m)
    acc += loop_rel[(j+m) & 255] * w_loop[m*256 + n];
  WB[n*832 + 576 + j] = sat16(acc);
}

__global__ void k_cvt_x(const float* __restrict__ in, _Float16* __restrict__ out, int n8){
  int t = blockIdx.x*256 + threadIdx.x;
  if (t >= n8) return;
  const float4* p = (const float4*)in + (size_t)t*2;
  float4 v0 = p[0], v1 = p[1];
  f16x8 o;
  o[0]=sat16(v0.x); o[1]=sat16(v0.y); o[2]=sat16(v0.z); o[3]=sat16(v0.w);
  o[4]=sat16(v1.x); o[5]=sat16(v1.y); o[6]=sat16(v1.z); o[7]=sat16(v1.w);
  ((f16x8*)out)[t] = o;
}

__global__ void k_deg(const int* __restrict__ ei, int* __restrict__ deg){
  int j = blockIdx.x*256 + threadIdx.x;
  if (j >= TWOE) return;
  int d = (j >= EE) ? 1 : 0;
  atomicAdd(&deg[d*NN + iclamp(ei[j], 0, NN-1)], 1);
}

__global__ void k_dinv(const int* __restrict__ deg, float* __restrict__ dinv){
  int t = blockIdx.x*256 + threadIdx.x;
  if (t >= 2*NN) return;
  int c = deg[t];
  dinv[t] = (c > 0) ? rsqrtf((float)c) : 0.f;
}

// C[M,N](ldc) = A[M,K](lda) * Bt[N,K](ldb)^T, fp32 accum, optional C-accumulate
template<typename OT, bool ACC>
__global__ __launch_bounds__(256) void k_gemm(const _Float16* __restrict__ A, int lda,
                                              const _Float16* __restrict__ Bt, int ldb,
                                              OT* __restrict__ C, int ldc,
                                              int M, int N, int K){
  __shared__ _Float16 Ash[128*40];
  __shared__ _Float16 Bsh[128*40];
  const int tid = threadIdx.x;
  const int lane = tid & 63;
  const int wv = tid >> 6;
  const int bm = blockIdx.x*128, bn = blockIdx.y*128;
  const int wm = (wv >> 1)*64, wn = (wv & 1)*64;
  const int sr = tid >> 1;
  const int sc = (tid & 1)*16;
  const int fr = lane & 15;
  const int fk = (lane >> 4)*8;
  f32x4 acc[4][4] = {};
  for (int kt = 0; kt < K; kt += 32){
    float4 a0 = make_float4(0.f,0.f,0.f,0.f), a1 = a0, b0 = a0, b1 = a0;
    if (bm + sr < M){
      const float4* p = (const float4*)(A + (size_t)(bm+sr)*lda + kt + sc);
      a0 = p[0]; a1 = p[1];
    }
    if (bn + sr < N){
      const float4* p = (const float4*)(Bt + (size_t)(bn+sr)*ldb + kt + sc);
      b0 = p[0]; b1 = p[1];
    }
    __syncthreads();
    *(float4*)&Ash[sr*40 + sc]     = a0;
    *(float4*)&Ash[sr*40 + sc + 8] = a1;
    *(float4*)&Bsh[sr*40 + sc]     = b0;
    *(float4*)&Bsh[sr*40 + sc + 8] = b1;
    __syncthreads();
    f16x8 af[4], bf_[4];
    #pragma unroll
    for (int i = 0; i < 4; ++i) af[i]  = *(const f16x8*)&Ash[(wm + i*16 + fr)*40 + fk];
    #pragma unroll
    for (int j = 0; j < 4; ++j) bf_[j] = *(const f16x8*)&Bsh[(wn + j*16 + fr)*40 + fk];
    #pragma unroll
    for (int i = 0; i < 4; ++i)
      #pragma unroll
      for (int j = 0; j < 4; ++j)
        acc[i][j] = __builtin_amdgcn_mfma_f32_16x16x32_f16(af[i], bf_[j], acc[i][j], 0, 0, 0);
  }
  const int cr = (lane >> 4)*4;
  const int cc = lane & 15;
  #pragma unroll
  for (int i = 0; i < 4; ++i)
    #pragma unroll
    for (int j = 0; j < 4; ++j)
      #pragma unroll
      for (int r = 0; r < 4; ++r){
        int row = bm + wm + i*16 + cr + r;
        int col = bn + wn + j*16 + cc;
        if (row < M && col < N){
          size_t idx = (size_t)row*ldc + col;
          float v = acc[i][j][r];
          if (ACC) v += (float)C[idx];
          C[idx] = (OT)sanit(v);
        }
      }
}

// CM[q] = conj(Xhat[ent]) * Rhat[rel], f16, zero-padded to 288
__global__ void k_cmul_qual(const _Float16* __restrict__ Xhat, const _Float16* __restrict__ Rhat,
                            const int* __restrict__ quals, int qbase,
                            _Float16* __restrict__ CM){
  int gt = blockIdx.x*256 + threadIdx.x;
  int wid = gt >> 6, lane = gt & 63;
  if (wid >= QCH) return;
  int qi  = qbase + wid;
  int rel = iclamp(quals[qi], 0, 500);
  int ent = iclamp(quals[TWOQ + qi], 0, NN-1);
  const unsigned int* xa = (const unsigned int*)(Xhat + (size_t)ent*288);
  const unsigned int* rb = (const unsigned int*)(Rhat + (size_t)rel*288);
  unsigned int* dst = (unsigned int*)(CM + (size_t)wid*288);
  for (int b = lane; b < 144; b += 64){
    unsigned int o = 0;
    if (b < 129){
      HU ua, ur; ua.u = xa[b]; ur.u = rb[b];
      float ax = (float)ua.h[0], ay = (float)ua.h[1];
      float rx = (float)ur.h[0], ry = (float)ur.h[1];
      HU uo;
      uo.h[0] = sat16(ax*rx + ay*ry);
      uo.h[1] = sat16(ax*ry - ay*rx);
      o = uo.u;
    }
    dst[b] = o;
  }
}

// AGG[dst] += 0.2*norm * conj(Xhat[src]) * Yhat[q]
__global__ void k_scatter_qual(const _Float16* __restrict__ Xhat, const _Float16* __restrict__ Yhat,
                               const int* __restrict__ ei, const int* __restrict__ quals,
                               const float* __restrict__ dinv, int qbase, int d,
                               float* __restrict__ AGG){
  int gt = blockIdx.x*256 + threadIdx.x;
  int wid = gt >> 6, lane = gt & 63;
  if (wid >= QCH) return;
  int qi = qbase + wid;
  int e  = iclamp(quals[2*TWOQ + qi], 0, EE-1);
  int j  = d*EE + e;
  int src = iclamp(ei[j], 0, NN-1);
  int dst = iclamp(ei[TWOE + j], 0, NN-1);
  float coef = 0.2f * dinv[d*NN + src] * dinv[d*NN + dst];
  if (coef == 0.f) return;
  const unsigned int* xa = (const unsigned int*)(Xhat + (size_t)src*288);
  const unsigned int* yb = (const unsigned int*)(Yhat + (size_t)wid*288);
  float* out = AGG + (size_t)dst*288;
  for (int b = lane; b < 129; b += 64){
    HU a, y; a.u = xa[b]; y.u = yb[b];
    float ax=(float)a.h[0], ay=(float)a.h[1], yx=(float)y.h[0], yy=(float)y.h[1];
    atomAddF(out + 2*b,     coef*(ax*yx + ay*yy));
    atomAddF(out + 2*b + 1, coef*(ax*yy - ay*yx));
  }
}

// AGG[dst] += 0.8*norm * conj(Xhat[src]) * Rhat[etype]
__global__ void k_scatter_edge(const _Float16* __restrict__ Xhat, const _Float16* __restrict__ Rhat,
                               const int* __restrict__ ei, const int* __restrict__ et,
                               const float* __restrict__ dinv, int d,
                               float* __restrict__ AGG){
  int gt = blockIdx.x*256 + threadIdx.x;
  int wid = gt >> 6, lane = gt & 63;
  if (wid >= EE) return;
  int j = d*EE + wid;
  int src = iclamp(ei[j], 0, NN-1);
  int dst = iclamp(ei[TWOE + j], 0, NN-1);
  int ty  = iclamp(et[j], 0, 500);
  float coef = 0.8f * dinv[d*NN + src] * dinv[d*NN + dst];
  if (coef == 0.f) return;
  const unsigned int* xa = (const unsigned int*)(Xhat + (size_t)src*288);
  const unsigned int* rb = (const unsigned int*)(Rhat + (size_t)ty*288);
  float* out = AGG + (size_t)dst*288;
  for (int b = lane; b < 129; b += 64){
    HU a, r; a.u = xa[b]; r.u = rb[b];
    float ax=(float)a.h[0], ay=(float)a.h[1], rx=(float)r.h[0], ry=(float)r.h[1];
    atomAddF(out + 2*b,     coef*(ax*rx + ay*ry));
    atomAddF(out + 2*b + 1, coef*(ax*ry - ay*rx));
  }
}

__global__ void k_conv_agg(const float* __restrict__ in, _Float16* __restrict__ out, int n8){
  int t = blockIdx.x*256 + threadIdx.x;
  if (t >= n8) return;
  const float4* p = (const float4*)in + (size_t)t*2;
  float4 v0 = p[0], v1 = p[1];
  f16x8 o;
  o[0]=sat16(v0.x); o[1]=sat16(v0.y); o[2]=sat16(v0.z); o[3]=sat16(v0.w);
  o[4]=sat16(v1.x); o[5]=sat16(v1.y); o[6]=sat16(v1.z); o[7]=sat16(v1.w);
  ((f16x8*)out)[t] = o;
}

__global__ void k_bnstats(const float* __restrict__ opre, float* __restrict__ bns){
  int col = threadIdx.x;
  int r0 = blockIdx.x*250, r1 = r0 + 250;
  float s1 = 0.f, s2 = 0.f;
  for (int r = r0; r < r1; ++r){
    float v = opre[(size_t)r*256 + col];
    s1 += v; s2 += v*v;
  }
  atomAddF(&bns[col], s1);
  atomAddF(&bns[256 + col], s2);
}

__global__ void k_bnfinal(float* __restrict__ bns, const float* __restrict__ gamma,
                          const float* __restrict__ beta){
  int col = threadIdx.x;
  float mean = bns[col] * (1.f/NN);
  float var  = bns[256 + col] * (1.f/NN) - mean*mean;
  var = fmaxf(var, 0.f);
  // BN of (acc/3 + bias) == (acc-mean_acc)/sqrt(var_acc + 9*eps); bias cancels
  float g = gamma[col] * rsqrtf(var + 9e-5f);
  float b = beta[col] - mean*g;
  bns[512 + col] = sanit(g);
  bns[768 + col] = sanit(b);
}

__global__ void k_ent(const float* __restrict__ opre, const float* __restrict__ bns,
                      float* __restrict__ out){
  int t = blockIdx.x*256 + threadIdx.x;
  if (t >= NN*64) return;
  float4 v = ((const float4*)opre)[t];
  int col = (t & 63)*4;
  float g0 = bns[512+col],   b0 = bns[768+col];
  float g1 = bns[512+col+1], b1 = bns[768+col+1];
  float g2 = bns[512+col+2], b2 = bns[768+col+2];
  float g3 = bns[512+col+3], b3 = bns[768+col+3];
  float4 o;
  o.x = sanit(tanhf(v.x*g0 + b0));
  o.y = sanit(tanhf(v.y*g1 + b1));
  o.z = sanit(tanhf(v.z*g2 + b2));
  o.w = sanit(tanhf(v.w*g3 + b3));
  ((float4*)out)[t] = o;
}

__global__ void k_rel_out(const float* __restrict__ ral32, const float* __restrict__ w_rel,
                          float* __restrict__ out){
  int r = blockIdx.x, n = threadIdx.x;
  float acc = 0.f;
  for (int k = 0; k < 256; ++k)
    acc += ral32[r*256 + k] * w_rel[k*256 + n];
  out[12800000 + r*256 + n] = sanit(acc);
}

extern "C" void kernel_launch(void* const* d_in, const int* in_sizes, int n_in,
                              void* d_out, int out_size, void* d_ws, size_t ws_size,
                              hipStream_t stream){
  (void)in_sizes; (void)n_in;
  if (ws_size < WS_NEED){
    hipMemsetAsync(d_out, 0, (size_t)out_size*4, stream);
    return;
  }
  const float* x        = (const float*)d_in[0];
  const float* rel_emb  = (const float*)d_in[1];
  const float* w_in     = (const float*)d_in[2];
  const float* w_out_   = (const float*)d_in[3];
  const float* w_loop   = (const float*)d_in[4];
  const float* w_rel    = (const float*)d_in[5];
  const float* w_q      = (const float*)d_in[6];
  const float* loop_rel = (const float*)d_in[7];
  const float* gamma    = (const float*)d_in[9];
  const float* beta     = (const float*)d_in[10];
  const int* ei    = (const int*)d_in[11];
  const int* et    = (const int*)d_in[12];
  const int* quals = (const int*)d_in[13];
  float* out = (float*)d_out;
  char* W = (char*)d_ws;
  _Float16* xh    = (_Float16*)(W + O_XH);
  _Float16* AGGh  = (_Float16*)(W + O_XH);
  _Float16* Xhat  = (_Float16*)(W + O_XHAT);
  float*    AGG   = (float*)(W + O_AGG);
  float*    opre  = (float*)(W + O_OPRE);
  _Float16* CM    = (_Float16*)(W + O_CM);
  _Float16* Yhat  = (_Float16*)(W + O_YH);
  _Float16* FR    = (_Float16*)(W + O_FR);
  _Float16* FI2   = (_Float16*)(W + O_FI2);
  _Float16* T1    = (_Float16*)(W + O_T1);
  _Float16* G     = (_Float16*)(W + O_G);
  _Float16* WB    = (_Float16*)(W + O_WB);
  _Float16* wqn   = (_Float16*)(W + O_WQN);
  _Float16* wint  = (_Float16*)(W + O_WINT);
  _Float16* woutt = (_Float16*)(W + O_WOUT);
  _Float16* ral16 = (_Float16*)(W + O_RAL16);
  float*    ral32 = (float*)(W + O_RAL32);
  _Float16* Rhat  = (_Float16*)(W + O_RHAT);
  int*      deg   = (int*)(W + O_DEG);
  float*    dinv  = (float*)(W + O_DINV);
  float*    bns   = (float*)(W + O_BNS);

  // Deterministic slate; remove once green.
  hipMemsetAsync(W, 0, WS_NEED, stream);

  k_gen_dft <<<288, 256, 0, stream>>>(FR, FI2);
  k_gen_misc<<<501, 256, 0, stream>>>(w_in, w_out_, w_q, rel_emb, loop_rel,
                                      wqn, wint, woutt, ral32, ral16);
  k_gen_bw  <<<256, 256, 0, stream>>>(loop_rel, w_loop, WB);
  k_cvt_x   <<<6250, 256, 0, stream>>>(x, xh, 1600000);
  k_deg     <<<2344, 256, 0, stream>>>(ei, deg);
  k_dinv    <<<391, 256, 0, stream>>>(deg, dinv);

  // T1 = FR @ wq^T ; G = T1 @ FI2^T  (qual chain fused: G = Fr.Wq^T.Fi^T)
  k_gemm<_Float16,false><<<dim3(3,2), 256, 0, stream>>>(FR, 256, wqn, 256, T1, 256, 288, 256, 256);
  k_gemm<_Float16,false><<<dim3(3,3), 256, 0, stream>>>(T1, 256, FI2, 256, G, 288, 288, 288, 256);
  // WB[:,0:288] = (Fi.W_in) transposed-pack ; WB[:,288:576] same for w_out
  k_gemm<_Float16,false><<<dim3(2,3), 256, 0, stream>>>(wint, 256, FI2, 256, WB, 832, 256, 288, 256);
  k_gemm<_Float16,false><<<dim3(2,3), 256, 0, stream>>>(woutt, 256, FI2, 256, WB + 288, 832, 256, 288, 256);

  // Xhat = x @ FR^T ; Rhat = rel_all @ FR^T
  k_gemm<_Float16,false><<<dim3(391,3), 256, 0, stream>>>(xh, 256, FR, 256, Xhat, 288, NN, 288, 256);
  k_gemm<_Float16,false><<<dim3(4,3),  256, 0, stream>>>(ral16, 256, FR, 256, Rhat, 288, 501, 288, 256);

  // opre = x @ BW  (self-loop term)
  k_gemm<float,false><<<dim3(391,2), 256, 0, stream>>>(xh, 256, WB + 576, 832, opre, 256, NN, 256, 256);

  for (int d = 0; d < 2; ++d){
    hipMemsetAsync(AGG, 0, 57600000, stream);
    for (int c = 0; c < 8; ++c){
      int qbase = d*100000 + c*QCH;
      k_cmul_qual<<<3125, 256, 0, stream>>>(Xhat, Rhat, quals, qbase, CM);
      k_gemm<_Float16,false><<<dim3(98,3), 256, 0, stream>>>(CM, 288, G, 288, Yhat, 288, QCH, 288, 288);
      k_scatter_qual<<<3125, 256, 0, stream>>>(Xhat, Yhat, ei, quals, dinv, qbase, d, AGG);
    }
    k_scatter_edge<<<75000, 256, 0, stream>>>(Xhat, Rhat, ei, et, dinv, d, AGG);
    k_conv_agg<<<7032, 256, 0, stream>>>(AGG, AGGh, 1800000);
    k_gemm<float,true><<<dim3(391,2), 256, 0, stream>>>(AGGh, 288, WB + (size_t)d*288, 832,
                                                        opre, 256, NN, 256, 288);
  }

  k_bnstats<<<200, 256, 0, stream>>>(opre, bns);
  k_bnfinal<<<1, 256, 0, stream>>>(bns, gamma, beta);
  k_ent<<<12500, 256, 0, stream>>>(opre, bns, out);
  k_rel_out<<<500, 256, 0, stream>>>(ral32, w_rel, out);
}

// Round 5
// 1251.590 us; speedup vs baseline: 1.7337x; 1.7337x over previous
//
#include <hip/hip_runtime.h>

typedef __attribute__((ext_vector_type(8))) _Float16 f16x8;
typedef __attribute__((ext_vector_type(4))) float f32x4;

#define NN   50000
#define EE   300000
#define TWOE 600000
#define TWOQ 200000
#define QCH  12500

// ---- workspace layout (bytes), total ~179.1 MB (ws >= 184 MB proven OK) ----
static constexpr size_t O_XH   = 0;           // xh f16 [N,256]; later AGGh f16 [N,288]
static constexpr size_t O_XHAT = 28800000;    // f16 [N,288]
static constexpr size_t O_YH   = 57600000;    // f16 [100000,288] per-direction Yhat
static constexpr size_t O_OPRE = 115200000;   // f32 [N,256]
static constexpr size_t O_CM   = 166400000;   // f16 [QCH,288]
static constexpr size_t O_FR   = 173600000;            // f16 [288,256]
static constexpr size_t O_FI2  = O_FR   + 147456;      // f16 [288,256]
static constexpr size_t O_T1   = O_FI2  + 147456;      // f16 [288,256]
static constexpr size_t O_G    = O_T1   + 147456;      // f16 [288,288]
static constexpr size_t O_WB   = O_G    + 165888;      // f16 [256,832]
static constexpr size_t O_WQN  = O_WB   + 425984;      // f16 [256,256]
static constexpr size_t O_WINT = O_WQN  + 131072;      // f16 [256,256]
static constexpr size_t O_WOUT = O_WINT + 131072;      // f16 [256,256]
static constexpr size_t O_RAL16= O_WOUT + 131072;      // f16 [501,256]
static constexpr size_t O_RAL32= O_RAL16+ 256512;      // f32 [501,256]
static constexpr size_t O_RHAT = O_RAL32+ 513024;      // f16 [501,288]
static constexpr size_t O_DEG  = O_RHAT + 288576;      // int [2,N]
static constexpr size_t O_DINV = O_DEG  + 400000;      // f32 [2,N]
static constexpr size_t O_BNS  = O_DINV + 400000;      // f32 [1024]
static constexpr size_t O_CNT  = O_BNS  + 4096;        // int [N]
static constexpr size_t O_PTR  = O_CNT  + 200000;      // int [N+1]
static constexpr size_t O_CUR  = O_PTR  + 200004;      // int [N]
static constexpr size_t O_ITEMS= O_CUR  + 200000;      // int [400000]
static constexpr size_t WS_NEED= O_ITEMS+ 1600000;

__device__ __forceinline__ float sanit(float v){
  v = (v == v) ? v : 0.f;
  return fminf(60000.f, fmaxf(-60000.f, v));
}
__device__ __forceinline__ _Float16 sat16(float v){ return (_Float16)sanit(v); }
__device__ __forceinline__ int iclamp(int v, int lo, int hi){
  return v < lo ? lo : (v > hi ? hi : v);
}
__device__ __forceinline__ void atomAddF(float* p, float v){
  __hip_atomic_fetch_add(p, v, __ATOMIC_RELAXED, __HIP_MEMORY_SCOPE_AGENT);
}
union HU { unsigned int u; _Float16 h[2]; };

// FR[f][t]: f=2m -> cos(2pi m t/256), f=2m+1 -> -sin; rows 258..287 zero.
// FI2[k][j]: irfft coeff, freq-comp k, time j.
__global__ void k_gen_dft(_Float16* __restrict__ FR, _Float16* __restrict__ FI2){
  int t = blockIdx.x*256 + threadIdx.x;
  if (t >= 288*256) return;
  const float step = 0.024543692606170259f; // 2*pi/256
  {
    int f = t >> 8, tt = t & 255;
    float v = 0.f;
    if (f < 258){
      int m = f >> 1;
      float ang = (float)((tt*m) & 255) * step;
      v = (f & 1) ? -sinf(ang) : cosf(ang);
    }
    FR[t] = (_Float16)v;
  }
  {
    int k = t >> 8, j = t & 255;
    float v = 0.f;
    if (k < 258){
      int m = k >> 1;
      float w = (m==0 || m==128) ? (1.f/256.f) : (2.f/256.f);
      float ang = (float)((j*m) & 255) * step;
      v = (k & 1) ? -w*sinf(ang) : w*cosf(ang);
    }
    FI2[t] = (_Float16)v;
  }
}

__global__ void k_gen_misc(const float* __restrict__ w_in, const float* __restrict__ w_out,
                           const float* __restrict__ w_q, const float* __restrict__ rel_embed,
                           const float* __restrict__ loop_rel,
                           _Float16* __restrict__ wqn, _Float16* __restrict__ wint,
                           _Float16* __restrict__ woutt,
                           float* __restrict__ ral32, _Float16* __restrict__ ral16){
  int t = blockIdx.x*256 + threadIdx.x;
  if (t >= 501*256) return;
  if (t < 65536){
    int j = t >> 8, n = t & 255;
    wqn[t] = sat16(w_q[t]);
    wint[n*256 + j]  = sat16(w_in[t]);
    woutt[n*256 + j] = sat16(w_out[t]);
  }
  float rv = (t < 128000) ? rel_embed[t] : loop_rel[t - 128000];
  rv = sanit(rv);
  ral32[t] = rv; ral16[t] = (_Float16)rv;
}

// WB[n][576+j] = sum_m loop_rel[(j+m)%256] * w_loop[m][n]
__global__ void k_gen_bw(const float* __restrict__ loop_rel, const float* __restrict__ w_loop,
                         _Float16* __restrict__ WB){
  int t = blockIdx.x*256 + threadIdx.x;
  if (t >= 65536) return;
  int j = t >> 8, n = t & 255;
  float acc = 0.f;
  for (int m = 0; m < 256; ++m)
    acc += loop_rel[(j+m) & 255] * w_loop[m*256 + n];
  WB[n*832 + 576 + j] = sat16(acc);
}

__global__ void k_cvt_x(const float* __restrict__ in, _Float16* __restrict__ out, int n8){
  int t = blockIdx.x*256 + threadIdx.x;
  if (t >= n8) return;
  const float4* p = (const float4*)in + (size_t)t*2;
  float4 v0 = p[0], v1 = p[1];
  f16x8 o;
  o[0]=sat16(v0.x); o[1]=sat16(v0.y); o[2]=sat16(v0.z); o[3]=sat16(v0.w);
  o[4]=sat16(v1.x); o[5]=sat16(v1.y); o[6]=sat16(v1.z); o[7]=sat16(v1.w);
  ((f16x8*)out)[t] = o;
}

__global__ void k_deg(const int* __restrict__ ei, int* __restrict__ deg){
  int j = blockIdx.x*256 + threadIdx.x;
  if (j >= TWOE) return;
  int d = (j >= EE) ? 1 : 0;
  atomicAdd(&deg[d*NN + iclamp(ei[j], 0, NN-1)], 1);
}

__global__ void k_dinv(const int* __restrict__ deg, float* __restrict__ dinv){
  int t = blockIdx.x*256 + threadIdx.x;
  if (t >= 2*NN) return;
  int c = deg[t];
  dinv[t] = (c > 0) ? rsqrtf((float)c) : 0.f;
}

// C[M,N](ldc) = A[M,K](lda) * Bt[N,K](ldb)^T, fp32 accum, optional C-accumulate
template<typename OT, bool ACC>
__global__ __launch_bounds__(256) void k_gemm(const _Float16* __restrict__ A, int lda,
                                              const _Float16* __restrict__ Bt, int ldb,
                                              OT* __restrict__ C, int ldc,
                                              int M, int N, int K){
  __shared__ _Float16 Ash[128*40];
  __shared__ _Float16 Bsh[128*40];
  const int tid = threadIdx.x;
  const int lane = tid & 63;
  const int wv = tid >> 6;
  const int bm = blockIdx.x*128, bn = blockIdx.y*128;
  const int wm = (wv >> 1)*64, wn = (wv & 1)*64;
  const int sr = tid >> 1;
  const int sc = (tid & 1)*16;
  const int fr = lane & 15;
  const int fk = (lane >> 4)*8;
  f32x4 acc[4][4] = {};
  for (int kt = 0; kt < K; kt += 32){
    float4 a0 = make_float4(0.f,0.f,0.f,0.f), a1 = a0, b0 = a0, b1 = a0;
    if (bm + sr < M){
      const float4* p = (const float4*)(A + (size_t)(bm+sr)*lda + kt + sc);
      a0 = p[0]; a1 = p[1];
    }
    if (bn + sr < N){
      const float4* p = (const float4*)(Bt + (size_t)(bn+sr)*ldb + kt + sc);
      b0 = p[0]; b1 = p[1];
    }
    __syncthreads();
    *(float4*)&Ash[sr*40 + sc]     = a0;
    *(float4*)&Ash[sr*40 + sc + 8] = a1;
    *(float4*)&Bsh[sr*40 + sc]     = b0;
    *(float4*)&Bsh[sr*40 + sc + 8] = b1;
    __syncthreads();
    f16x8 af[4], bf_[4];
    #pragma unroll
    for (int i = 0; i < 4; ++i) af[i]  = *(const f16x8*)&Ash[(wm + i*16 + fr)*40 + fk];
    #pragma unroll
    for (int j = 0; j < 4; ++j) bf_[j] = *(const f16x8*)&Bsh[(wn + j*16 + fr)*40 + fk];
    #pragma unroll
    for (int i = 0; i < 4; ++i)
      #pragma unroll
      for (int j = 0; j < 4; ++j)
        acc[i][j] = __builtin_amdgcn_mfma_f32_16x16x32_f16(af[i], bf_[j], acc[i][j], 0, 0, 0);
  }
  const int cr = (lane >> 4)*4;
  const int cc = lane & 15;
  #pragma unroll
  for (int i = 0; i < 4; ++i)
    #pragma unroll
    for (int j = 0; j < 4; ++j)
      #pragma unroll
      for (int r = 0; r < 4; ++r){
        int row = bm + wm + i*16 + cr + r;
        int col = bn + wn + j*16 + cc;
        if (row < M && col < N){
          size_t idx = (size_t)row*ldc + col;
          float v = acc[i][j][r];
          if (ACC) v += (float)C[idx];
          C[idx] = (OT)sanit(v);
        }
      }
}

// CM[q] = conj(Xhat[ent]) * Rhat[rel], f16, zero-padded to 288
__global__ void k_cmul_qual(const _Float16* __restrict__ Xhat, const _Float16* __restrict__ Rhat,
                            const int* __restrict__ quals, int qbase,
                            _Float16* __restrict__ CM){
  int gt = blockIdx.x*256 + threadIdx.x;
  int wid = gt >> 6, lane = gt & 63;
  if (wid >= QCH) return;
  int qi  = qbase + wid;
  int rel = iclamp(quals[qi], 0, 500);
  int ent = iclamp(quals[TWOQ + qi], 0, NN-1);
  const unsigned int* xa = (const unsigned int*)(Xhat + (size_t)ent*288);
  const unsigned int* rb = (const unsigned int*)(Rhat + (size_t)rel*288);
  unsigned int* dst = (unsigned int*)(CM + (size_t)wid*288);
  for (int b = lane; b < 144; b += 64){
    unsigned int o = 0;
    if (b < 129){
      HU ua, ur; ua.u = xa[b]; ur.u = rb[b];
      float ax = (float)ua.h[0], ay = (float)ua.h[1];
      float rx = (float)ur.h[0], ry = (float)ur.h[1];
      HU uo;
      uo.h[0] = sat16(ax*rx + ay*ry);
      uo.h[1] = sat16(ax*ry - ay*rx);
      o = uo.u;
    }
    dst[b] = o;
  }
}

// ---- CSR build: count items per dst node, scan, fill ----
__global__ void k_cnt(const int* __restrict__ ei, const int* __restrict__ quals,
                      int d, int* __restrict__ cnt){
  int t = blockIdx.x*256 + threadIdx.x;
  if (t < EE){
    atomicAdd(&cnt[iclamp(ei[TWOE + d*EE + t], 0, NN-1)], 1);
  } else if (t < EE + 100000){
    int q = t - EE;
    int e = iclamp(quals[2*TWOQ + d*100000 + q], 0, EE-1);
    atomicAdd(&cnt[iclamp(ei[TWOE + d*EE + e], 0, NN-1)], 1);
  }
}

// exclusive prefix sum cnt[0..NN) -> ptr[0..NN]
__global__ void k_scan(const int* __restrict__ cnt, int* __restrict__ ptr){
  __shared__ int sums[256];
  int t = threadIdx.x;
  const int CH = (NN + 255)/256;
  int base = t*CH;
  int s = 0;
  for (int i = 0; i < CH; ++i){ int idx = base+i; if (idx < NN) s += cnt[idx]; }
  sums[t] = s; __syncthreads();
  if (t == 0){ int run = 0; for (int i = 0; i < 256; ++i){ int v = sums[i]; sums[i] = run; run += v; } }
  __syncthreads();
  int run = sums[t];
  for (int i = 0; i < CH; ++i){
    int idx = base+i;
    if (idx < NN){ ptr[idx] = run; run += cnt[idx]; }
  }
  if (t == 255) ptr[NN] = run;
}

// fill buckets: edge e -> id e (>=0); qual q -> id ~q (<0)
__global__ void k_fill(const int* __restrict__ ei, const int* __restrict__ quals,
                       int d, int* __restrict__ cursor, int* __restrict__ items){
  int t = blockIdx.x*256 + threadIdx.x;
  if (t < EE){
    int dst = iclamp(ei[TWOE + d*EE + t], 0, NN-1);
    int pos = atomicAdd(&cursor[dst], 1);
    items[iclamp(pos, 0, 400000-1)] = t;
  } else if (t < EE + 100000){
    int q = t - EE;
    int e = iclamp(quals[2*TWOQ + d*100000 + q], 0, EE-1);
    int dst = iclamp(ei[TWOE + d*EE + e], 0, NN-1);
    int pos = atomicAdd(&cursor[dst], 1);
    items[iclamp(pos, 0, 400000-1)] = ~q;
  }
}

// ---- gather-aggregate: one 128-thread block per dst node, no atomics ----
// AGGh[node] = sum over items: coef * conj(Xhat[src]) * B   (B = Rhat[type] or Yhat[q])
__global__ __launch_bounds__(128) void k_agg(const _Float16* __restrict__ Xhat,
                                             const _Float16* __restrict__ Rhat,
                                             const _Float16* __restrict__ Yhat,
                                             const int* __restrict__ ptr,
                                             const int* __restrict__ items,
                                             const int* __restrict__ ei,
                                             const int* __restrict__ et,
                                             const int* __restrict__ quals,
                                             const float* __restrict__ dinv, int d,
                                             _Float16* __restrict__ AGGh){
  int node = blockIdx.x;
  int t = threadIdx.x;  // complex bin t (0..127); t==0 also handles bin 128
  int beg = ptr[node], end = ptr[node+1];
  float dI = dinv[d*NN + node];
  float ax_ = 0.f, ay_ = 0.f, ex = 0.f, ey = 0.f;
  for (int it = beg; it < end; ++it){
    int id = items[it];
    const unsigned int* brow;
    int src; float w;
    if (id >= 0){            // edge
      int j = d*EE + id;
      src = iclamp(ei[j], 0, NN-1);
      w = 0.8f;
      brow = (const unsigned int*)(Rhat + (size_t)iclamp(et[j], 0, 500)*288);
    } else {                 // qual
      int q = ~id;
      int e = iclamp(quals[2*TWOQ + d*100000 + q], 0, EE-1);
      int j = d*EE + e;
      src = iclamp(ei[j], 0, NN-1);
      w = 0.2f;
      brow = (const unsigned int*)(Yhat + (size_t)q*288);
    }
    float coef = w * dinv[d*NN + src] * dI;
    const unsigned int* xrow = (const unsigned int*)(Xhat + (size_t)src*288);
    HU a, b; a.u = xrow[t]; b.u = brow[t];
    float axv=(float)a.h[0], ayv=(float)a.h[1], bxv=(float)b.h[0], byv=(float)b.h[1];
    ax_ += coef*(axv*bxv + ayv*byv);
    ay_ += coef*(axv*byv - ayv*bxv);
    if (t == 0){
      HU a2, b2; a2.u = xrow[128]; b2.u = brow[128];
      float a2x=(float)a2.h[0], a2y=(float)a2.h[1], b2x=(float)b2.h[0], b2y=(float)b2.h[1];
      ex += coef*(a2x*b2x + a2y*b2y);
      ey += coef*(a2x*b2y - a2y*b2x);
    }
  }
  unsigned int* orow = (unsigned int*)(AGGh + (size_t)node*288);
  HU o; o.h[0] = sat16(ax_); o.h[1] = sat16(ay_);
  orow[t] = o.u;
  if (t == 0){
    HU o2; o2.h[0] = sat16(ex); o2.h[1] = sat16(ey);
    orow[128] = o2.u;
  }
}

__global__ void k_bnstats(const float* __restrict__ opre, float* __restrict__ bns){
  int col = threadIdx.x;
  int r0 = blockIdx.x*250, r1 = r0 + 250;
  float s1 = 0.f, s2 = 0.f;
  for (int r = r0; r < r1; ++r){
    float v = opre[(size_t)r*256 + col];
    s1 += v; s2 += v*v;
  }
  atomAddF(&bns[col], s1);
  atomAddF(&bns[256 + col], s2);
}

__global__ void k_bnfinal(float* __restrict__ bns, const float* __restrict__ gamma,
                          const float* __restrict__ beta){
  int col = threadIdx.x;
  float mean = bns[col] * (1.f/NN);
  float var  = bns[256 + col] * (1.f/NN) - mean*mean;
  var = fmaxf(var, 0.f);
  // BN of (acc/3 + bias) == (acc-mean_acc)/sqrt(var_acc + 9*eps); bias cancels
  float g = gamma[col] * rsqrtf(var + 9e-5f);
  float b = beta[col] - mean*g;
  bns[512 + col] = sanit(g);
  bns[768 + col] = sanit(b);
}

__global__ void k_ent(const float* __restrict__ opre, const float* __restrict__ bns,
                      float* __restrict__ out){
  int t = blockIdx.x*256 + threadIdx.x;
  if (t >= NN*64) return;
  float4 v = ((const float4*)opre)[t];
  int col = (t & 63)*4;
  float g0 = bns[512+col],   b0 = bns[768+col];
  float g1 = bns[512+col+1], b1 = bns[768+col+1];
  float g2 = bns[512+col+2], b2 = bns[768+col+2];
  float g3 = bns[512+col+3], b3 = bns[768+col+3];
  float4 o;
  o.x = sanit(tanhf(v.x*g0 + b0));
  o.y = sanit(tanhf(v.y*g1 + b1));
  o.z = sanit(tanhf(v.z*g2 + b2));
  o.w = sanit(tanhf(v.w*g3 + b3));
  ((float4*)out)[t] = o;
}

__global__ void k_rel_out(const float* __restrict__ ral32, const float* __restrict__ w_rel,
                          float* __restrict__ out){
  int r = blockIdx.x, n = threadIdx.x;
  float acc = 0.f;
  for (int k = 0; k < 256; ++k)
    acc += ral32[r*256 + k] * w_rel[k*256 + n];
  out[12800000 + r*256 + n] = sanit(acc);
}

extern "C" void kernel_launch(void* const* d_in, const int* in_sizes, int n_in,
                              void* d_out, int out_size, void* d_ws, size_t ws_size,
                              hipStream_t stream){
  (void)in_sizes; (void)n_in;
  if (ws_size < WS_NEED){
    hipMemsetAsync(d_out, 0, (size_t)out_size*4, stream);
    return;
  }
  const float* x        = (const float*)d_in[0];
  const float* rel_emb  = (const float*)d_in[1];
  const float* w_in     = (const float*)d_in[2];
  const float* w_out_   = (const float*)d_in[3];
  const float* w_loop   = (const float*)d_in[4];
  const float* w_rel    = (const float*)d_in[5];
  const float* w_q      = (const float*)d_in[6];
  const float* loop_rel = (const float*)d_in[7];
  const float* gamma    = (const float*)d_in[9];
  const float* beta     = (const float*)d_in[10];
  const int* ei    = (const int*)d_in[11];
  const int* et    = (const int*)d_in[12];
  const int* quals = (const int*)d_in[13];
  float* out = (float*)d_out;
  char* W = (char*)d_ws;
  _Float16* xh    = (_Float16*)(W + O_XH);
  _Float16* AGGh  = (_Float16*)(W + O_XH);
  _Float16* Xhat  = (_Float16*)(W + O_XHAT);
  _Float16* Yhat  = (_Float16*)(W + O_YH);
  float*    opre  = (float*)(W + O_OPRE);
  _Float16* CM    = (_Float16*)(W + O_CM);
  _Float16* FR    = (_Float16*)(W + O_FR);
  _Float16* FI2   = (_Float16*)(W + O_FI2);
  _Float16* T1    = (_Float16*)(W + O_T1);
  _Float16* G     = (_Float16*)(W + O_G);
  _Float16* WB    = (_Float16*)(W + O_WB);
  _Float16* wqn   = (_Float16*)(W + O_WQN);
  _Float16* wint  = (_Float16*)(W + O_WINT);
  _Float16* woutt = (_Float16*)(W + O_WOUT);
  _Float16* ral16 = (_Float16*)(W + O_RAL16);
  float*    ral32 = (float*)(W + O_RAL32);
  _Float16* Rhat  = (_Float16*)(W + O_RHAT);
  int*      deg   = (int*)(W + O_DEG);
  float*    dinv  = (float*)(W + O_DINV);
  float*    bns   = (float*)(W + O_BNS);
  int*      cnt   = (int*)(W + O_CNT);
  int*      ptr   = (int*)(W + O_PTR);
  int*      cur   = (int*)(W + O_CUR);
  int*      items = (int*)(W + O_ITEMS);

  // Deterministic slate (also zeroes deg/bns accumulators). ~30us.
  hipMemsetAsync(W, 0, WS_NEED, stream);

  k_gen_dft <<<288, 256, 0, stream>>>(FR, FI2);
  k_gen_misc<<<501, 256, 0, stream>>>(w_in, w_out_, w_q, rel_emb, loop_rel,
                                      wqn, wint, woutt, ral32, ral16);
  k_gen_bw  <<<256, 256, 0, stream>>>(loop_rel, w_loop, WB);
  k_cvt_x   <<<6250, 256, 0, stream>>>(x, xh, 1600000);
  k_deg     <<<2344, 256, 0, stream>>>(ei, deg);
  k_dinv    <<<391, 256, 0, stream>>>(deg, dinv);

  // T1 = FR @ wq^T ; G = T1 @ FI2^T  (qual chain fused: G = Fr.Wq^T.Fi^T)
  k_gemm<_Float16,false><<<dim3(3,2), 256, 0, stream>>>(FR, 256, wqn, 256, T1, 256, 288, 256, 256);
  k_gemm<_Float16,false><<<dim3(3,3), 256, 0, stream>>>(T1, 256, FI2, 256, G, 288, 288, 288, 256);
  // WB[:,0:288] = (Fi.W_in) transposed-pack ; WB[:,288:576] same for w_out
  k_gemm<_Float16,false><<<dim3(2,3), 256, 0, stream>>>(wint, 256, FI2, 256, WB, 832, 256, 288, 256);
  k_gemm<_Float16,false><<<dim3(2,3), 256, 0, stream>>>(woutt, 256, FI2, 256, WB + 288, 832, 256, 288, 256);

  // Xhat = x @ FR^T ; Rhat = rel_all @ FR^T
  k_gemm<_Float16,false><<<dim3(391,3), 256, 0, stream>>>(xh, 256, FR, 256, Xhat, 288, NN, 288, 256);
  k_gemm<_Float16,false><<<dim3(4,3),  256, 0, stream>>>(ral16, 256, FR, 256, Rhat, 288, 501, 288, 256);

  // opre = x @ BW  (self-loop term; overwrites, later GEMMs accumulate)
  k_gemm<float,false><<<dim3(391,2), 256, 0, stream>>>(xh, 256, WB + 576, 832, opre, 256, NN, 256, 256);

  for (int d = 0; d < 2; ++d){
    // Yhat (full direction) = (conj(Xhat[ent])*Rhat[rel]) @ G^T, chunked
    for (int c = 0; c < 8; ++c){
      int qbase = d*100000 + c*QCH;
      k_cmul_qual<<<3125, 256, 0, stream>>>(Xhat, Rhat, quals, qbase, CM);
      k_gemm<_Float16,false><<<dim3(98,3), 256, 0, stream>>>(CM, 288, G, 288,
                                                             Yhat + (size_t)c*QCH*288, 288,
                                                             QCH, 288, 288);
    }
    // CSR by dst node over 400k items (300k edges + 100k quals)
    hipMemsetAsync(cnt, 0, 200000, stream);
    k_cnt <<<1563, 256, 0, stream>>>(ei, quals, d, cnt);
    k_scan<<<1, 256, 0, stream>>>(cnt, ptr);
    hipMemcpyAsync(cur, ptr, 200000, hipMemcpyDeviceToDevice, stream);
    k_fill<<<1563, 256, 0, stream>>>(ei, quals, d, cur, items);
    // gather-aggregate, no atomics, writes f16 AGGh directly
    k_agg<<<NN, 128, 0, stream>>>(Xhat, Rhat, Yhat, ptr, items, ei, et, quals, dinv, d, AGGh);
    // opre += AGGh @ (Fi.W_d)
    k_gemm<float,true><<<dim3(391,2), 256, 0, stream>>>(AGGh, 288, WB + (size_t)d*288, 832,
                                                        opre, 256, NN, 256, 288);
  }

  k_bnstats<<<200, 256, 0, stream>>>(opre, bns);
  k_bnfinal<<<1, 256, 0, stream>>>(bns, gamma, beta);
  k_ent<<<12500, 256, 0, stream>>>(opre, bns, out);
  k_rel_out<<<500, 256, 0, stream>>>(ral32, w_rel, out);
}

// Round 6
// 1015.001 us; speedup vs baseline: 2.1378x; 1.2331x over previous
//
#include <hip/hip_runtime.h>

typedef __attribute__((ext_vector_type(8))) _Float16 f16x8;
typedef __attribute__((ext_vector_type(4))) float f32x4;

#define NN   50000
#define EE   300000
#define TWOE 600000
#define TWOQ 200000

// ---- workspace layout (bytes), all offsets 64-aligned, total ~174.5 MB ----
static constexpr size_t O_XH   = 0;            // xh f16 [50048,256]; AGGh f16 [50048,288] aliases
static constexpr size_t O_XHAT = 28827648;     // f16 [50048,288]
static constexpr size_t O_YH   = 57655296;     // f16 [100096,288] per-direction Yhat
static constexpr size_t O_OPRE = 115310592;    // f32 [50048,256]
static constexpr size_t O_FR   = 166559744;    // f16 [384,256]
static constexpr size_t O_FI2  = O_FR   + 196608;   // f16 [384,256]
static constexpr size_t O_T1   = O_FI2  + 196608;   // f16 [384,256]
static constexpr size_t O_G    = O_T1   + 196608;   // f16 [384,288]
static constexpr size_t O_WB   = O_G    + 221184;   // f16 [256,832]
static constexpr size_t O_WQN  = O_WB   + 425984;   // f16 [256,256]
static constexpr size_t O_WINT = O_WQN  + 131072;   // f16 [256,256]
static constexpr size_t O_WOUT = O_WINT + 131072;   // f16 [256,256]
static constexpr size_t O_RAL16= O_WOUT + 131072;   // f16 [512,256]
static constexpr size_t O_RAL32= O_RAL16+ 262144;   // f32 [501,256]
static constexpr size_t O_RHAT = O_RAL32+ 513024;   // f16 [512,288]
static constexpr size_t O_DEG  = O_RHAT + 294912;   // int [2,N]
static constexpr size_t O_DINV = O_DEG  + 400000;   // f32 [2,N]
static constexpr size_t O_BNS  = O_DINV + 400000;   // f32 [1024]
static constexpr size_t O_CNT  = O_BNS  + 4096;     // int [2N]
static constexpr size_t O_PTR  = O_CNT  + 400000;   // int [2N+1]
static constexpr size_t O_CUR  = O_PTR  + 400064;   // int [2N]
static constexpr size_t O_ITEMS= O_CUR  + 400000;   // int [800000]
static constexpr size_t WS_NEED= O_ITEMS+ 3200000;

__device__ __forceinline__ float sanit(float v){
  v = (v == v) ? v : 0.f;
  return fminf(60000.f, fmaxf(-60000.f, v));
}
__device__ __forceinline__ _Float16 sat16(float v){ return (_Float16)sanit(v); }
__device__ __forceinline__ int iclamp(int v, int lo, int hi){
  return v < lo ? lo : (v > hi ? hi : v);
}
__device__ __forceinline__ void atomAddF(float* p, float v){
  __hip_atomic_fetch_add(p, v, __ATOMIC_RELAXED, __HIP_MEMORY_SCOPE_AGENT);
}
union HU { unsigned int u; _Float16 h[2]; };

__device__ __forceinline__ unsigned int cmulh(unsigned int ua, unsigned int ub){
  HU a, b, o; a.u = ua; b.u = ub;
  float ax=(float)a.h[0], ay=(float)a.h[1], bx=(float)b.h[0], by=(float)b.h[1];
  o.h[0] = (_Float16)(ax*bx + ay*by);
  o.h[1] = (_Float16)(ax*by - ay*bx);
  return o.u;
}

// FR[f][t]: f=2m -> cos(2pi m t/256), f=2m+1 -> -sin; rows 258..287 zero (rows 288+ pad).
// FI2[k][j]: irfft coeff, freq-comp k, time j; rows 258..287 zero.
__global__ void k_gen_dft(_Float16* __restrict__ FR, _Float16* __restrict__ FI2){
  int t = blockIdx.x*256 + threadIdx.x;
  if (t >= 288*256) return;
  const float step = 0.024543692606170259f; // 2*pi/256
  {
    int f = t >> 8, tt = t & 255;
    float v = 0.f;
    if (f < 258){
      int m = f >> 1;
      float ang = (float)((tt*m) & 255) * step;
      v = (f & 1) ? -sinf(ang) : cosf(ang);
    }
    FR[t] = (_Float16)v;
  }
  {
    int k = t >> 8, j = t & 255;
    float v = 0.f;
    if (k < 258){
      int m = k >> 1;
      float w = (m==0 || m==128) ? (1.f/256.f) : (2.f/256.f);
      float ang = (float)((j*m) & 255) * step;
      v = (k & 1) ? -w*sinf(ang) : w*cosf(ang);
    }
    FI2[t] = (_Float16)v;
  }
}

__global__ void k_gen_misc(const float* __restrict__ w_in, const float* __restrict__ w_out,
                           const float* __restrict__ w_q, const float* __restrict__ rel_embed,
                           const float* __restrict__ loop_rel,
                           _Float16* __restrict__ wqn, _Float16* __restrict__ wint,
                           _Float16* __restrict__ woutt,
                           float* __restrict__ ral32, _Float16* __restrict__ ral16){
  int t = blockIdx.x*256 + threadIdx.x;
  if (t >= 501*256) return;
  if (t < 65536){
    int j = t >> 8, n = t & 255;
    wqn[t] = sat16(w_q[t]);
    wint[n*256 + j]  = sat16(w_in[t]);
    woutt[n*256 + j] = sat16(w_out[t]);
  }
  float rv = (t < 128000) ? rel_embed[t] : loop_rel[t - 128000];
  rv = sanit(rv);
  ral32[t] = rv; ral16[t] = (_Float16)rv;
}

// WB[n][576+j] = sum_m loop_rel[(j+m)%256] * w_loop[m][n]
__global__ void k_gen_bw(const float* __restrict__ loop_rel, const float* __restrict__ w_loop,
                         _Float16* __restrict__ WB){
  int t = blockIdx.x*256 + threadIdx.x;
  if (t >= 65536) return;
  int j = t >> 8, n = t & 255;
  float acc = 0.f;
  for (int m = 0; m < 256; ++m)
    acc += loop_rel[(j+m) & 255] * w_loop[m*256 + n];
  WB[n*832 + 576 + j] = sat16(acc);
}

__global__ void k_cvt_x(const float* __restrict__ in, _Float16* __restrict__ out, int n8){
  int t = blockIdx.x*256 + threadIdx.x;
  if (t >= n8) return;
  const float4* p = (const float4*)in + (size_t)t*2;
  float4 v0 = p[0], v1 = p[1];
  f16x8 o;
  o[0]=sat16(v0.x); o[1]=sat16(v0.y); o[2]=sat16(v0.z); o[3]=sat16(v0.w);
  o[4]=sat16(v1.x); o[5]=sat16(v1.y); o[6]=sat16(v1.z); o[7]=sat16(v1.w);
  ((f16x8*)out)[t] = o;
}

__global__ void k_deg(const int* __restrict__ ei, int* __restrict__ deg){
  int j = blockIdx.x*256 + threadIdx.x;
  if (j >= TWOE) return;
  int d = (j >= EE) ? 1 : 0;
  atomicAdd(&deg[d*NN + iclamp(ei[j], 0, NN-1)], 1);
}

__global__ void k_dinv(const int* __restrict__ deg, float* __restrict__ dinv){
  int t = blockIdx.x*256 + threadIdx.x;
  if (t >= 2*NN) return;
  int c = deg[t];
  dinv[t] = (c > 0) ? rsqrtf((float)c) : 0.f;
}

// C[M,N](ldc) = A[.,K](lda) @ Bt[.,K](ldb)^T; fp32 accum; UNGUARDED loads
// (A rows padded to gridDim.x*128, Bt rows padded to gridDim.y*128, K%32==0).
// Store: rows unguarded (padded C), cols guarded vs N.
template<typename OT, bool ACC>
__global__ __launch_bounds__(256) void k_gemm(const _Float16* __restrict__ A, int lda,
                                              const _Float16* __restrict__ Bt, int ldb,
                                              OT* __restrict__ C, int ldc,
                                              int N, int K){
  __shared__ _Float16 Ash[128*40];
  __shared__ _Float16 Bsh[128*40];
  const int tid = threadIdx.x;
  const int lane = tid & 63;
  const int wv = tid >> 6;
  const int bm = blockIdx.x*128, bn = blockIdx.y*128;
  const int wm = (wv >> 1)*64, wn = (wv & 1)*64;
  const int sr = tid >> 1;
  const int sc = (tid & 1)*16;
  const int fr = lane & 15;
  const int fk = (lane >> 4)*8;
  const _Float16* pa = A + (size_t)(bm+sr)*lda + sc;
  const _Float16* pb = Bt + (size_t)(bn+sr)*ldb + sc;
  f32x4 acc[4][4] = {};
  for (int kt = 0; kt < K; kt += 32){
    float4 a0 = *(const float4*)(pa);
    float4 a1 = *(const float4*)(pa + 8);
    float4 b0 = *(const float4*)(pb);
    float4 b1 = *(const float4*)(pb + 8);
    pa += 32; pb += 32;
    __syncthreads();
    *(float4*)&Ash[sr*40 + sc]     = a0;
    *(float4*)&Ash[sr*40 + sc + 8] = a1;
    *(float4*)&Bsh[sr*40 + sc]     = b0;
    *(float4*)&Bsh[sr*40 + sc + 8] = b1;
    __syncthreads();
    f16x8 af[4], bf_[4];
    #pragma unroll
    for (int i = 0; i < 4; ++i) af[i]  = *(const f16x8*)&Ash[(wm + i*16 + fr)*40 + fk];
    #pragma unroll
    for (int j = 0; j < 4; ++j) bf_[j] = *(const f16x8*)&Bsh[(wn + j*16 + fr)*40 + fk];
    #pragma unroll
    for (int i = 0; i < 4; ++i)
      #pragma unroll
      for (int j = 0; j < 4; ++j)
        acc[i][j] = __builtin_amdgcn_mfma_f32_16x16x32_f16(af[i], bf_[j], acc[i][j], 0, 0, 0);
  }
  const int cr = (lane >> 4)*4;
  const int cc = lane & 15;
  #pragma unroll
  for (int i = 0; i < 4; ++i)
    #pragma unroll
    for (int j = 0; j < 4; ++j){
      int col = bn + wn + j*16 + cc;
      if (col < N){
        #pragma unroll
        for (int r = 0; r < 4; ++r){
          size_t idx = (size_t)(bm + wm + i*16 + cr + r)*ldc + col;
          float v = acc[i][j][r];
          if (ACC) v += (float)C[idx];
          C[idx] = (OT)sanit(v);
        }
      }
    }
}

// Fused qual GEMM: Yhat[q] = (conj(Xhat[ent_q]) .* Rhat[rel_q]) @ G^T
// A-tile computed in-register during staging (no CM buffer).
__global__ __launch_bounds__(256) void k_qgemm(const _Float16* __restrict__ Xhat,
                                               const _Float16* __restrict__ Rhat,
                                               const int* __restrict__ quals, int d,
                                               const _Float16* __restrict__ G,
                                               _Float16* __restrict__ Yhat){
  __shared__ _Float16 Ash[128*40];
  __shared__ _Float16 Bsh[128*40];
  const int tid = threadIdx.x;
  const int lane = tid & 63;
  const int wv = tid >> 6;
  const int bm = blockIdx.x*128, bn = blockIdx.y*128;
  const int wm = (wv >> 1)*64, wn = (wv & 1)*64;
  const int sr = tid >> 1;
  const int h  = tid & 1;
  const int fr = lane & 15;
  const int fk = (lane >> 4)*8;
  int q = bm + sr; if (q > 99999) q = 99999;
  int qi = d*100000 + q;
  int rel = iclamp(quals[qi], 0, 500);
  int ent = iclamp(quals[TWOQ + qi], 0, NN-1);
  const unsigned int* xr = (const unsigned int*)(Xhat + (size_t)ent*288);
  const unsigned int* rr = (const unsigned int*)(Rhat + (size_t)rel*288);
  const _Float16* pb = G + (size_t)(bn+sr)*288 + h*16;
  f32x4 acc[4][4] = {};
  for (int kt = 0; kt < 288; kt += 32){
    int kb = (kt >> 1) + h*8;           // first complex bin of this 16-elem half
    uint4 xa0 = *(const uint4*)(xr + kb);
    uint4 xa1 = *(const uint4*)(xr + kb + 4);
    uint4 ra0 = *(const uint4*)(rr + kb);
    uint4 ra1 = *(const uint4*)(rr + kb + 4);
    float4 b0 = *(const float4*)(pb);
    float4 b1 = *(const float4*)(pb + 8);
    pb += 32;
    uint4 oa0, oa1;
    oa0.x = cmulh(xa0.x, ra0.x); oa0.y = cmulh(xa0.y, ra0.y);
    oa0.z = cmulh(xa0.z, ra0.z); oa0.w = cmulh(xa0.w, ra0.w);
    oa1.x = cmulh(xa1.x, ra1.x); oa1.y = cmulh(xa1.y, ra1.y);
    oa1.z = cmulh(xa1.z, ra1.z); oa1.w = cmulh(xa1.w, ra1.w);
    __syncthreads();
    *(uint4*)&Ash[sr*40 + h*16]     = oa0;
    *(uint4*)&Ash[sr*40 + h*16 + 8] = oa1;
    *(float4*)&Bsh[sr*40 + h*16]     = b0;
    *(float4*)&Bsh[sr*40 + h*16 + 8] = b1;
    __syncthreads();
    f16x8 af[4], bf_[4];
    #pragma unroll
    for (int i = 0; i < 4; ++i) af[i]  = *(const f16x8*)&Ash[(wm + i*16 + fr)*40 + fk];
    #pragma unroll
    for (int j = 0; j < 4; ++j) bf_[j] = *(const f16x8*)&Bsh[(wn + j*16 + fr)*40 + fk];
    #pragma unroll
    for (int i = 0; i < 4; ++i)
      #pragma unroll
      for (int j = 0; j < 4; ++j)
        acc[i][j] = __builtin_amdgcn_mfma_f32_16x16x32_f16(af[i], bf_[j], acc[i][j], 0, 0, 0);
  }
  const int cr = (lane >> 4)*4;
  const int cc = lane & 15;
  #pragma unroll
  for (int i = 0; i < 4; ++i)
    #pragma unroll
    for (int j = 0; j < 4; ++j){
      int col = bn + wn + j*16 + cc;
      if (col < 288){
        #pragma unroll
        for (int r = 0; r < 4; ++r){
          size_t idx = (size_t)(bm + wm + i*16 + cr + r)*288 + col;
          Yhat[idx] = sat16(acc[i][j][r]);
        }
      }
    }
}

// ---- unified CSR over both directions: 800k items into buckets by (d,dst) ----
__global__ void k_cnt(const int* __restrict__ ei, const int* __restrict__ quals,
                      int* __restrict__ cnt){
  int t = blockIdx.x*256 + threadIdx.x;
  if (t < TWOE){
    int d = (t >= EE) ? 1 : 0;
    atomicAdd(&cnt[d*NN + iclamp(ei[TWOE + t], 0, NN-1)], 1);
  } else if (t < TWOE + TWOQ){
    int qg = t - TWOE;
    int d = (qg >= 100000) ? 1 : 0;
    int e = iclamp(quals[2*TWOQ + qg], 0, EE-1);
    int j = d*EE + e;
    atomicAdd(&cnt[d*NN + iclamp(ei[TWOE + j], 0, NN-1)], 1);
  }
}

__global__ void k_scan(const int* __restrict__ cnt, int* __restrict__ ptr){
  __shared__ int sums[256];
  int t = threadIdx.x;
  const int M = 2*NN;
  const int CH = (M + 255)/256;
  int base = t*CH;
  int s = 0;
  for (int i = 0; i < CH; ++i){ int idx = base+i; if (idx < M) s += cnt[idx]; }
  sums[t] = s; __syncthreads();
  if (t == 0){ int run = 0; for (int i = 0; i < 256; ++i){ int v = sums[i]; sums[i] = run; run += v; } }
  __syncthreads();
  int run = sums[t];
  for (int i = 0; i < CH; ++i){
    int idx = base+i;
    if (idx < M){ ptr[idx] = run; run += cnt[idx]; }
  }
  if (t == 255) ptr[M] = run;
}

__global__ void k_fill(const int* __restrict__ ei, const int* __restrict__ quals,
                       int* __restrict__ cursor, int* __restrict__ items){
  int t = blockIdx.x*256 + threadIdx.x;
  if (t < TWOE){
    int d = (t >= EE) ? 1 : 0;
    int dst = iclamp(ei[TWOE + t], 0, NN-1);
    int pos = atomicAdd(&cursor[d*NN + dst], 1);
    items[iclamp(pos, 0, 800000-1)] = t;          // edge: global edge index j
  } else if (t < TWOE + TWOQ){
    int qg = t - TWOE;
    int d = (qg >= 100000) ? 1 : 0;
    int e = iclamp(quals[2*TWOQ + qg], 0, EE-1);
    int j = d*EE + e;
    int dst = iclamp(ei[TWOE + j], 0, NN-1);
    int pos = atomicAdd(&cursor[d*NN + dst], 1);
    items[iclamp(pos, 0, 800000-1)] = ~qg;        // qual: ~global qual index
  }
}

// ---- gather-aggregate, software-pipelined; writes f16 AGGh (bins 129..143 zeroed) ----
__global__ __launch_bounds__(128) void k_agg(const _Float16* __restrict__ Xhat,
                                             const _Float16* __restrict__ Rhat,
                                             const _Float16* __restrict__ Yhat,
                                             const int* __restrict__ ptr,
                                             const int* __restrict__ items,
                                             const int* __restrict__ ei,
                                             const int* __restrict__ et,
                                             const int* __restrict__ quals,
                                             const float* __restrict__ dinv, int d,
                                             _Float16* __restrict__ AGGh){
  int node = blockIdx.x;
  int t = threadIdx.x;
  int gnode = d*NN + node;
  int beg = ptr[gnode], end = ptr[gnode+1];
  float dI = dinv[gnode];
  float ax_ = 0.f, ay_ = 0.f, ex = 0.f;
  const unsigned int* xrow = nullptr;
  const unsigned int* brow = nullptr;
  float coef = 0.f;
  auto resolve = [&](int it, const unsigned int*& xr, const unsigned int*& br, float& cf){
    int id = items[it];
    int j; float w;
    if (id >= 0){
      j = id; w = 0.8f;
      br = (const unsigned int*)(Rhat + (size_t)iclamp(et[j], 0, 500)*288);
    } else {
      int qg = ~id;
      int e = iclamp(quals[2*TWOQ + qg], 0, EE-1);
      j = d*EE + e; w = 0.2f;
      br = (const unsigned int*)(Yhat + (size_t)(qg - d*100000)*288);
    }
    int src = iclamp(ei[j], 0, NN-1);
    cf = w * dinv[d*NN + src] * dI;
    xr = (const unsigned int*)(Xhat + (size_t)src*288);
  };
  if (beg < end) resolve(beg, xrow, brow, coef);
  for (int it = beg; it < end; ++it){
    HU a, b; a.u = xrow[t]; b.u = brow[t];
    float a128 = (float)((const _Float16*)xrow)[256];   // uniform broadcast
    float b128 = (float)((const _Float16*)brow)[256];
    const unsigned int* xn = nullptr; const unsigned int* bn_ = nullptr; float cn = 0.f;
    if (it + 1 < end) resolve(it + 1, xn, bn_, cn);
    float axv=(float)a.h[0], ayv=(float)a.h[1], bxv=(float)b.h[0], byv=(float)b.h[1];
    ax_ += coef*(axv*bxv + ayv*byv);
    ay_ += coef*(axv*byv - ayv*bxv);
    ex  += coef*a128*b128;
    if (it + 1 < end){ xrow = xn; brow = bn_; coef = cn; }
  }
  unsigned int* orow = (unsigned int*)(AGGh + (size_t)node*288);
  HU o; o.h[0] = sat16(ax_); o.h[1] = sat16(ay_);
  orow[t] = o.u;
  if (t < 16){
    HU o2; o2.h[0] = (t == 0) ? sat16(ex) : (_Float16)0.f; o2.h[1] = (_Float16)0.f;
    orow[128 + t] = o2.u;
  }
}

__global__ void k_bnstats(const float* __restrict__ opre, float* __restrict__ bns){
  int col = threadIdx.x;
  int r0 = blockIdx.x*64, r1 = r0 + 64; if (r1 > NN) r1 = NN;
  float s1 = 0.f, s2 = 0.f;
  for (int r = r0; r < r1; ++r){
    float v = opre[(size_t)r*256 + col];
    s1 += v; s2 += v*v;
  }
  atomAddF(&bns[col], s1);
  atomAddF(&bns[256 + col], s2);
}

__global__ void k_bnfinal(float* __restrict__ bns, const float* __restrict__ gamma,
                          const float* __restrict__ beta){
  int col = threadIdx.x;
  float mean = bns[col] * (1.f/NN);
  float var  = bns[256 + col] * (1.f/NN) - mean*mean;
  var = fmaxf(var, 0.f);
  // BN of (acc/3 + bias) == (acc-mean_acc)/sqrt(var_acc + 9*eps); bias cancels
  float g = gamma[col] * rsqrtf(var + 9e-5f);
  float b = beta[col] - mean*g;
  bns[512 + col] = sanit(g);
  bns[768 + col] = sanit(b);
}

__global__ void k_ent(const float* __restrict__ opre, const float* __restrict__ bns,
                      float* __restrict__ out){
  int t = blockIdx.x*256 + threadIdx.x;
  if (t >= NN*64) return;
  float4 v = ((const float4*)opre)[t];
  int col = (t & 63)*4;
  float g0 = bns[512+col],   b0 = bns[768+col];
  float g1 = bns[512+col+1], b1 = bns[768+col+1];
  float g2 = bns[512+col+2], b2 = bns[768+col+2];
  float g3 = bns[512+col+3], b3 = bns[768+col+3];
  float4 o;
  o.x = sanit(tanhf(v.x*g0 + b0));
  o.y = sanit(tanhf(v.y*g1 + b1));
  o.z = sanit(tanhf(v.z*g2 + b2));
  o.w = sanit(tanhf(v.w*g3 + b3));
  ((float4*)out)[t] = o;
}

__global__ void k_rel_out(const float* __restrict__ ral32, const float* __restrict__ w_rel,
                          float* __restrict__ out){
  int r = blockIdx.x, n = threadIdx.x;
  float acc = 0.f;
  for (int k = 0; k < 256; ++k)
    acc += ral32[r*256 + k] * w_rel[k*256 + n];
  out[12800000 + r*256 + n] = sanit(acc);
}

extern "C" void kernel_launch(void* const* d_in, const int* in_sizes, int n_in,
                              void* d_out, int out_size, void* d_ws, size_t ws_size,
                              hipStream_t stream){
  (void)in_sizes; (void)n_in;
  if (ws_size < WS_NEED){
    hipMemsetAsync(d_out, 0, (size_t)out_size*4, stream);
    return;
  }
  const float* x        = (const float*)d_in[0];
  const float* rel_emb  = (const float*)d_in[1];
  const float* w_in     = (const float*)d_in[2];
  const float* w_out_   = (const float*)d_in[3];
  const float* w_loop   = (const float*)d_in[4];
  const float* w_rel    = (const float*)d_in[5];
  const float* w_q      = (const float*)d_in[6];
  const float* loop_rel = (const float*)d_in[7];
  const float* gamma    = (const float*)d_in[9];
  const float* beta     = (const float*)d_in[10];
  const int* ei    = (const int*)d_in[11];
  const int* et    = (const int*)d_in[12];
  const int* quals = (const int*)d_in[13];
  float* out = (float*)d_out;
  char* W = (char*)d_ws;
  _Float16* xh    = (_Float16*)(W + O_XH);
  _Float16* AGGh  = (_Float16*)(W + O_XH);
  _Float16* Xhat  = (_Float16*)(W + O_XHAT);
  _Float16* Yhat  = (_Float16*)(W + O_YH);
  float*    opre  = (float*)(W + O_OPRE);
  _Float16* FR    = (_Float16*)(W + O_FR);
  _Float16* FI2   = (_Float16*)(W + O_FI2);
  _Float16* T1    = (_Float16*)(W + O_T1);
  _Float16* G     = (_Float16*)(W + O_G);
  _Float16* WB    = (_Float16*)(W + O_WB);
  _Float16* wqn   = (_Float16*)(W + O_WQN);
  _Float16* wint  = (_Float16*)(W + O_WINT);
  _Float16* woutt = (_Float16*)(W + O_WOUT);
  _Float16* ral16 = (_Float16*)(W + O_RAL16);
  float*    ral32 = (float*)(W + O_RAL32);
  _Float16* Rhat  = (_Float16*)(W + O_RHAT);
  int*      deg   = (int*)(W + O_DEG);
  float*    dinv  = (float*)(W + O_DINV);
  float*    bns   = (float*)(W + O_BNS);
  int*      cnt   = (int*)(W + O_CNT);
  int*      ptr   = (int*)(W + O_PTR);
  int*      cur   = (int*)(W + O_CUR);
  int*      items = (int*)(W + O_ITEMS);

  hipMemsetAsync(deg, 0, 400000, stream);
  hipMemsetAsync(cnt, 0, 400000, stream);
  hipMemsetAsync(bns, 0, 4096, stream);

  k_gen_dft <<<288, 256, 0, stream>>>(FR, FI2);
  k_gen_misc<<<501, 256, 0, stream>>>(w_in, w_out_, w_q, rel_emb, loop_rel,
                                      wqn, wint, woutt, ral32, ral16);
  k_gen_bw  <<<256, 256, 0, stream>>>(loop_rel, w_loop, WB);
  k_cvt_x   <<<6250, 256, 0, stream>>>(x, xh, 1600000);
  k_deg     <<<2344, 256, 0, stream>>>(ei, deg);
  k_dinv    <<<391, 256, 0, stream>>>(deg, dinv);

  // unified CSR (both directions)
  k_cnt <<<3125, 256, 0, stream>>>(ei, quals, cnt);
  k_scan<<<1, 256, 0, stream>>>(cnt, ptr);
  hipMemcpyAsync(cur, ptr, 400000, hipMemcpyDeviceToDevice, stream);
  k_fill<<<3125, 256, 0, stream>>>(ei, quals, cur, items);

  // T1 = FR @ wqn^T ; G = T1 @ FI2^T   (G = Fr.Wq^T.Fi^T)
  k_gemm<_Float16,false><<<dim3(3,2), 256, 0, stream>>>(FR, 256, wqn, 256, T1, 256, 256, 256);
  k_gemm<_Float16,false><<<dim3(3,3), 256, 0, stream>>>(T1, 256, FI2, 256, G, 288, 288, 256);
  // WB[:,0:288] = (Fi.W_in)^T-pack ; WB[:,288:576] for w_out
  k_gemm<_Float16,false><<<dim3(2,3), 256, 0, stream>>>(wint, 256, FI2, 256, WB, 832, 288, 256);
  k_gemm<_Float16,false><<<dim3(2,3), 256, 0, stream>>>(woutt, 256, FI2, 256, WB + 288, 832, 288, 256);

  // Xhat = x @ FR^T ; Rhat = rel_all @ FR^T
  k_gemm<_Float16,false><<<dim3(391,3), 256, 0, stream>>>(xh, 256, FR, 256, Xhat, 288, 288, 256);
  k_gemm<_Float16,false><<<dim3(4,3),  256, 0, stream>>>(ral16, 256, FR, 256, Rhat, 288, 288, 256);

  // opre = x @ BW (self-loop)
  k_gemm<float,false><<<dim3(391,2), 256, 0, stream>>>(xh, 256, WB + 576, 832, opre, 256, 256, 256);

  for (int d = 0; d < 2; ++d){
    k_qgemm<<<dim3(782,3), 256, 0, stream>>>(Xhat, Rhat, quals, d, G, Yhat);
    k_agg<<<NN, 128, 0, stream>>>(Xhat, Rhat, Yhat, ptr, items, ei, et, quals, dinv, d, AGGh);
    k_gemm<float,true><<<dim3(391,2), 256, 0, stream>>>(AGGh, 288, WB + (size_t)d*288, 832,
                                                        opre, 256, 256, 288);
  }

  k_bnstats<<<782, 256, 0, stream>>>(opre, bns);
  k_bnfinal<<<1, 256, 0, stream>>>(bns, gamma, beta);
  k_ent<<<12500, 256, 0, stream>>>(opre, bns, out);
  k_rel_out<<<500, 256, 0, stream>>>(ral32, w_rel, out);
}

// Round 7
// 795.492 us; speedup vs baseline: 2.7278x; 1.2759x over previous
//
#include <hip/hip_runtime.h>

typedef __attribute__((ext_vector_type(8))) _Float16 f16x8;
typedef __attribute__((ext_vector_type(4))) float f32x4;

#define NN   50000
#define EE   300000
#define TWOE 600000
#define TWOQ 200000
#define SCB  98     // scan blocks of 1024 ints covering 2*NN=100000

// ---- workspace layout (bytes), all offsets 64-aligned, total ~174.5 MB ----
static constexpr size_t O_XH   = 0;            // xh f16 [50048,256]; AGGh f16 [50048,288] aliases
static constexpr size_t O_XHAT = 28827648;     // f16 [50048,288]
static constexpr size_t O_YH   = 57655296;     // f16 [100096,288] per-direction Yhat
static constexpr size_t O_OPRE = 115310592;    // f32 [50048,256]
static constexpr size_t O_FR   = 166559744;    // f16 [384,256]
static constexpr size_t O_FI2  = O_FR   + 196608;   // f16 [384,256]
static constexpr size_t O_T1   = O_FI2  + 196608;   // f16 [384,256]
static constexpr size_t O_G    = O_T1   + 196608;   // f16 [384,288]
static constexpr size_t O_WB   = O_G    + 221184;   // f16 [256,832]
static constexpr size_t O_WQN  = O_WB   + 425984;   // f16 [256,256]
static constexpr size_t O_WINT = O_WQN  + 131072;   // f16 [256,256]
static constexpr size_t O_WOUT = O_WINT + 131072;   // f16 [256,256]
static constexpr size_t O_RAL16= O_WOUT + 131072;   // f16 [512,256]
static constexpr size_t O_RAL32= O_RAL16+ 262144;   // f32 [501,256]
static constexpr size_t O_RHAT = O_RAL32+ 513024;   // f16 [512,288]
static constexpr size_t O_DEG  = O_RHAT + 294912;   // int [2,N]
static constexpr size_t O_DINV = O_DEG  + 400000;   // f32 [2,N]
static constexpr size_t O_BNS  = O_DINV + 400000;   // f32 [1024]
static constexpr size_t O_CNT  = O_BNS  + 4096;     // int [2N]
static constexpr size_t O_PTR  = O_CNT  + 400000;   // int [2N+1]
static constexpr size_t O_CUR  = O_PTR  + 400064;   // int [2N]
static constexpr size_t O_BSUM = O_CUR  + 400000;   // int [128]
static constexpr size_t O_ITEMS= O_BSUM + 512;      // int [800000]
static constexpr size_t WS_NEED= O_ITEMS+ 3200000;

__device__ __forceinline__ float sanit(float v){
  v = (v == v) ? v : 0.f;
  return fminf(60000.f, fmaxf(-60000.f, v));
}
__device__ __forceinline__ _Float16 sat16(float v){ return (_Float16)sanit(v); }
__device__ __forceinline__ int iclamp(int v, int lo, int hi){
  return v < lo ? lo : (v > hi ? hi : v);
}
__device__ __forceinline__ void atomAddF(float* p, float v){
  __hip_atomic_fetch_add(p, v, __ATOMIC_RELAXED, __HIP_MEMORY_SCOPE_AGENT);
}
union HU { unsigned int u; _Float16 h[2]; };

__device__ __forceinline__ unsigned int cmulh(unsigned int ua, unsigned int ub){
  HU a, b, o; a.u = ua; b.u = ub;
  float ax=(float)a.h[0], ay=(float)a.h[1], bx=(float)b.h[0], by=(float)b.h[1];
  o.h[0] = (_Float16)(ax*bx + ay*by);
  o.h[1] = (_Float16)(ax*by - ay*bx);
  return o.u;
}

// FR[f][t]: f=2m -> cos(2pi m t/256), f=2m+1 -> -sin; rows 258..287 zero (rows 288+ pad).
// FI2[k][j]: irfft coeff, freq-comp k, time j; rows 258..287 zero.
__global__ void k_gen_dft(_Float16* __restrict__ FR, _Float16* __restrict__ FI2){
  int t = blockIdx.x*256 + threadIdx.x;
  if (t >= 288*256) return;
  const float step = 0.024543692606170259f; // 2*pi/256
  {
    int f = t >> 8, tt = t & 255;
    float v = 0.f;
    if (f < 258){
      int m = f >> 1;
      float ang = (float)((tt*m) & 255) * step;
      v = (f & 1) ? -sinf(ang) : cosf(ang);
    }
    FR[t] = (_Float16)v;
  }
  {
    int k = t >> 8, j = t & 255;
    float v = 0.f;
    if (k < 258){
      int m = k >> 1;
      float w = (m==0 || m==128) ? (1.f/256.f) : (2.f/256.f);
      float ang = (float)((j*m) & 255) * step;
      v = (k & 1) ? -w*sinf(ang) : w*cosf(ang);
    }
    FI2[t] = (_Float16)v;
  }
}

__global__ void k_gen_misc(const float* __restrict__ w_in, const float* __restrict__ w_out,
                           const float* __restrict__ w_q, const float* __restrict__ rel_embed,
                           const float* __restrict__ loop_rel,
                           _Float16* __restrict__ wqn, _Float16* __restrict__ wint,
                           _Float16* __restrict__ woutt,
                           float* __restrict__ ral32, _Float16* __restrict__ ral16){
  int t = blockIdx.x*256 + threadIdx.x;
  if (t >= 501*256) return;
  if (t < 65536){
    int j = t >> 8, n = t & 255;
    wqn[t] = sat16(w_q[t]);
    wint[n*256 + j]  = sat16(w_in[t]);
    woutt[n*256 + j] = sat16(w_out[t]);
  }
  float rv = (t < 128000) ? rel_embed[t] : loop_rel[t - 128000];
  rv = sanit(rv);
  ral32[t] = rv; ral16[t] = (_Float16)rv;
}

// WB[n][576+j] = sum_m loop_rel[(j+m)%256] * w_loop[m][n]
__global__ void k_gen_bw(const float* __restrict__ loop_rel, const float* __restrict__ w_loop,
                         _Float16* __restrict__ WB){
  int t = blockIdx.x*256 + threadIdx.x;
  if (t >= 65536) return;
  int j = t >> 8, n = t & 255;
  float acc = 0.f;
  for (int m = 0; m < 256; ++m)
    acc += loop_rel[(j+m) & 255] * w_loop[m*256 + n];
  WB[n*832 + 576 + j] = sat16(acc);
}

__global__ void k_cvt_x(const float* __restrict__ in, _Float16* __restrict__ out, int n8){
  int t = blockIdx.x*256 + threadIdx.x;
  if (t >= n8) return;
  const float4* p = (const float4*)in + (size_t)t*2;
  float4 v0 = p[0], v1 = p[1];
  f16x8 o;
  o[0]=sat16(v0.x); o[1]=sat16(v0.y); o[2]=sat16(v0.z); o[3]=sat16(v0.w);
  o[4]=sat16(v1.x); o[5]=sat16(v1.y); o[6]=sat16(v1.z); o[7]=sat16(v1.w);
  ((f16x8*)out)[t] = o;
}

__global__ void k_deg(const int* __restrict__ ei, int* __restrict__ deg){
  int j = blockIdx.x*256 + threadIdx.x;
  if (j >= TWOE) return;
  int d = (j >= EE) ? 1 : 0;
  atomicAdd(&deg[d*NN + iclamp(ei[j], 0, NN-1)], 1);
}

__global__ void k_dinv(const int* __restrict__ deg, float* __restrict__ dinv){
  int t = blockIdx.x*256 + threadIdx.x;
  if (t >= 2*NN) return;
  int c = deg[t];
  dinv[t] = (c > 0) ? rsqrtf((float)c) : 0.f;
}

// C[M,N](ldc) = A[.,K](lda) @ Bt[.,K](ldb)^T; fp32 accum; UNGUARDED loads
// (A rows padded to gridDim.x*128, Bt rows padded to gridDim.y*128, K%32==0).
template<typename OT, bool ACC>
__global__ __launch_bounds__(256) void k_gemm(const _Float16* __restrict__ A, int lda,
                                              const _Float16* __restrict__ Bt, int ldb,
                                              OT* __restrict__ C, int ldc,
                                              int N, int K){
  __shared__ _Float16 Ash[128*40];
  __shared__ _Float16 Bsh[128*40];
  const int tid = threadIdx.x;
  const int lane = tid & 63;
  const int wv = tid >> 6;
  const int bm = blockIdx.x*128, bn = blockIdx.y*128;
  const int wm = (wv >> 1)*64, wn = (wv & 1)*64;
  const int sr = tid >> 1;
  const int sc = (tid & 1)*16;
  const int fr = lane & 15;
  const int fk = (lane >> 4)*8;
  const _Float16* pa = A + (size_t)(bm+sr)*lda + sc;
  const _Float16* pb = Bt + (size_t)(bn+sr)*ldb + sc;
  f32x4 acc[4][4] = {};
  for (int kt = 0; kt < K; kt += 32){
    float4 a0 = *(const float4*)(pa);
    float4 a1 = *(const float4*)(pa + 8);
    float4 b0 = *(const float4*)(pb);
    float4 b1 = *(const float4*)(pb + 8);
    pa += 32; pb += 32;
    __syncthreads();
    *(float4*)&Ash[sr*40 + sc]     = a0;
    *(float4*)&Ash[sr*40 + sc + 8] = a1;
    *(float4*)&Bsh[sr*40 + sc]     = b0;
    *(float4*)&Bsh[sr*40 + sc + 8] = b1;
    __syncthreads();
    f16x8 af[4], bf_[4];
    #pragma unroll
    for (int i = 0; i < 4; ++i) af[i]  = *(const f16x8*)&Ash[(wm + i*16 + fr)*40 + fk];
    #pragma unroll
    for (int j = 0; j < 4; ++j) bf_[j] = *(const f16x8*)&Bsh[(wn + j*16 + fr)*40 + fk];
    #pragma unroll
    for (int i = 0; i < 4; ++i)
      #pragma unroll
      for (int j = 0; j < 4; ++j)
        acc[i][j] = __builtin_amdgcn_mfma_f32_16x16x32_f16(af[i], bf_[j], acc[i][j], 0, 0, 0);
  }
  const int cr = (lane >> 4)*4;
  const int cc = lane & 15;
  #pragma unroll
  for (int i = 0; i < 4; ++i)
    #pragma unroll
    for (int j = 0; j < 4; ++j){
      int col = bn + wn + j*16 + cc;
      if (col < N){
        #pragma unroll
        for (int r = 0; r < 4; ++r){
          size_t idx = (size_t)(bm + wm + i*16 + cr + r)*ldc + col;
          float v = acc[i][j][r];
          if (ACC) v += (float)C[idx];
          C[idx] = (OT)sanit(v);
        }
      }
    }
}

// Fused qual GEMM: Yhat[q] = (conj(Xhat[ent_q]) .* Rhat[rel_q]) @ G^T
__global__ __launch_bounds__(256) void k_qgemm(const _Float16* __restrict__ Xhat,
                                               const _Float16* __restrict__ Rhat,
                                               const int* __restrict__ quals, int d,
                                               const _Float16* __restrict__ G,
                                               _Float16* __restrict__ Yhat){
  __shared__ _Float16 Ash[128*40];
  __shared__ _Float16 Bsh[128*40];
  const int tid = threadIdx.x;
  const int lane = tid & 63;
  const int wv = tid >> 6;
  const int bm = blockIdx.x*128, bn = blockIdx.y*128;
  const int wm = (wv >> 1)*64, wn = (wv & 1)*64;
  const int sr = tid >> 1;
  const int h  = tid & 1;
  const int fr = lane & 15;
  const int fk = (lane >> 4)*8;
  int q = bm + sr; if (q > 99999) q = 99999;
  int qi = d*100000 + q;
  int rel = iclamp(quals[qi], 0, 500);
  int ent = iclamp(quals[TWOQ + qi], 0, NN-1);
  const unsigned int* xr = (const unsigned int*)(Xhat + (size_t)ent*288);
  const unsigned int* rr = (const unsigned int*)(Rhat + (size_t)rel*288);
  const _Float16* pb = G + (size_t)(bn+sr)*288 + h*16;
  f32x4 acc[4][4] = {};
  for (int kt = 0; kt < 288; kt += 32){
    int kb = (kt >> 1) + h*8;
    uint4 xa0 = *(const uint4*)(xr + kb);
    uint4 xa1 = *(const uint4*)(xr + kb + 4);
    uint4 ra0 = *(const uint4*)(rr + kb);
    uint4 ra1 = *(const uint4*)(rr + kb + 4);
    float4 b0 = *(const float4*)(pb);
    float4 b1 = *(const float4*)(pb + 8);
    pb += 32;
    uint4 oa0, oa1;
    oa0.x = cmulh(xa0.x, ra0.x); oa0.y = cmulh(xa0.y, ra0.y);
    oa0.z = cmulh(xa0.z, ra0.z); oa0.w = cmulh(xa0.w, ra0.w);
    oa1.x = cmulh(xa1.x, ra1.x); oa1.y = cmulh(xa1.y, ra1.y);
    oa1.z = cmulh(xa1.z, ra1.z); oa1.w = cmulh(xa1.w, ra1.w);
    __syncthreads();
    *(uint4*)&Ash[sr*40 + h*16]     = oa0;
    *(uint4*)&Ash[sr*40 + h*16 + 8] = oa1;
    *(float4*)&Bsh[sr*40 + h*16]     = b0;
    *(float4*)&Bsh[sr*40 + h*16 + 8] = b1;
    __syncthreads();
    f16x8 af[4], bf_[4];
    #pragma unroll
    for (int i = 0; i < 4; ++i) af[i]  = *(const f16x8*)&Ash[(wm + i*16 + fr)*40 + fk];
    #pragma unroll
    for (int j = 0; j < 4; ++j) bf_[j] = *(const f16x8*)&Bsh[(wn + j*16 + fr)*40 + fk];
    #pragma unroll
    for (int i = 0; i < 4; ++i)
      #pragma unroll
      for (int j = 0; j < 4; ++j)
        acc[i][j] = __builtin_amdgcn_mfma_f32_16x16x32_f16(af[i], bf_[j], acc[i][j], 0, 0, 0);
  }
  const int cr = (lane >> 4)*4;
  const int cc = lane & 15;
  #pragma unroll
  for (int i = 0; i < 4; ++i)
    #pragma unroll
    for (int j = 0; j < 4; ++j){
      int col = bn + wn + j*16 + cc;
      if (col < 288){
        #pragma unroll
        for (int r = 0; r < 4; ++r){
          size_t idx = (size_t)(bm + wm + i*16 + cr + r)*288 + col;
          Yhat[idx] = sat16(acc[i][j][r]);
        }
      }
    }
}

// ---- unified CSR over both directions ----
__global__ void k_cnt(const int* __restrict__ ei, const int* __restrict__ quals,
                      int* __restrict__ cnt){
  int t = blockIdx.x*256 + threadIdx.x;
  if (t < TWOE){
    int d = (t >= EE) ? 1 : 0;
    atomicAdd(&cnt[d*NN + iclamp(ei[TWOE + t], 0, NN-1)], 1);
  } else if (t < TWOE + TWOQ){
    int qg = t - TWOE;
    int d = (qg >= 100000) ? 1 : 0;
    int e = iclamp(quals[2*TWOQ + qg], 0, EE-1);
    int j = d*EE + e;
    atomicAdd(&cnt[d*NN + iclamp(ei[TWOE + j], 0, NN-1)], 1);
  }
}

// hierarchical exclusive scan of cnt[0..2N) -> ptr[0..2N], ptr[2N]=total
__global__ void k_scan1(const int* __restrict__ cnt, int* __restrict__ bsum){
  __shared__ int sh[256];
  int b = blockIdx.x, t = threadIdx.x;
  int base = b*1024 + t*4;
  int s = 0;
  #pragma unroll
  for (int i = 0; i < 4; ++i){ int idx = base + i; if (idx < 2*NN) s += cnt[idx]; }
  sh[t] = s; __syncthreads();
  for (int off = 128; off > 0; off >>= 1){
    if (t < off) sh[t] += sh[t + off];
    __syncthreads();
  }
  if (t == 0) bsum[b] = sh[0];
}

__global__ void k_scan2(int* __restrict__ bsum, int* __restrict__ ptr){
  if (threadIdx.x == 0){
    int run = 0;
    for (int i = 0; i < SCB; ++i){ int v = bsum[i]; bsum[i] = run; run += v; }
    ptr[2*NN] = run;
  }
}

__global__ void k_scan3(const int* __restrict__ cnt, const int* __restrict__ bsum,
                        int* __restrict__ ptr){
  __shared__ int sh[256];
  int b = blockIdx.x, t = threadIdx.x;
  int base = b*1024 + t*4;
  int v[4];
  int s = 0;
  #pragma unroll
  for (int i = 0; i < 4; ++i){
    int idx = base + i;
    v[i] = (idx < 2*NN) ? cnt[idx] : 0;
    s += v[i];
  }
  sh[t] = s; __syncthreads();
  // inclusive Hillis-Steele over thread sums
  for (int off = 1; off < 256; off <<= 1){
    int add = (t >= off) ? sh[t - off] : 0;
    __syncthreads();
    sh[t] += add;
    __syncthreads();
  }
  int off0 = bsum[b] + sh[t] - s;   // exclusive offset for this thread's first elem
  #pragma unroll
  for (int i = 0; i < 4; ++i){
    int idx = base + i;
    if (idx < 2*NN) ptr[idx] = off0;
    off0 += v[i];
  }
}

__global__ void k_fill(const int* __restrict__ ei, const int* __restrict__ quals,
                       int* __restrict__ cursor, int* __restrict__ items){
  int t = blockIdx.x*256 + threadIdx.x;
  if (t < TWOE){
    int d = (t >= EE) ? 1 : 0;
    int dst = iclamp(ei[TWOE + t], 0, NN-1);
    int pos = atomicAdd(&cursor[d*NN + dst], 1);
    items[iclamp(pos, 0, 800000-1)] = t;          // edge: global edge index j
  } else if (t < TWOE + TWOQ){
    int qg = t - TWOE;
    int d = (qg >= 100000) ? 1 : 0;
    int e = iclamp(quals[2*TWOQ + qg], 0, EE-1);
    int j = d*EE + e;
    int dst = iclamp(ei[TWOE + j], 0, NN-1);
    int pos = atomicAdd(&cursor[d*NN + dst], 1);
    items[iclamp(pos, 0, 800000-1)] = ~qg;        // qual: ~global qual index
  }
}

// ---- gather-aggregate, software-pipelined; writes f16 AGGh (bins 129..143 zeroed) ----
__global__ __launch_bounds__(128) void k_agg(const _Float16* __restrict__ Xhat,
                                             const _Float16* __restrict__ Rhat,
                                             const _Float16* __restrict__ Yhat,
                                             const int* __restrict__ ptr,
                                             const int* __restrict__ items,
                                             const int* __restrict__ ei,
                                             const int* __restrict__ et,
                                             const int* __restrict__ quals,
                                             const float* __restrict__ dinv, int d,
                                             _Float16* __restrict__ AGGh){
  int node = blockIdx.x;
  int t = threadIdx.x;
  int gnode = d*NN + node;
  int beg = ptr[gnode], end = ptr[gnode+1];
  float dI = dinv[gnode];
  float ax_ = 0.f, ay_ = 0.f, ex = 0.f;
  const unsigned int* xrow = nullptr;
  const unsigned int* brow = nullptr;
  float coef = 0.f;
  auto resolve = [&](int it, const unsigned int*& xr, const unsigned int*& br, float& cf){
    int id = items[it];
    int j; float w;
    if (id >= 0){
      j = id; w = 0.8f;
      br = (const unsigned int*)(Rhat + (size_t)iclamp(et[j], 0, 500)*288);
    } else {
      int qg = ~id;
      int e = iclamp(quals[2*TWOQ + qg], 0, EE-1);
      j = d*EE + e; w = 0.2f;
      br = (const unsigned int*)(Yhat + (size_t)(qg - d*100000)*288);
    }
    int src = iclamp(ei[j], 0, NN-1);
    cf = w * dinv[d*NN + src] * dI;
    xr = (const unsigned int*)(Xhat + (size_t)src*288);
  };
  if (beg < end) resolve(beg, xrow, brow, coef);
  for (int it = beg; it < end; ++it){
    HU a, b; a.u = xrow[t]; b.u = brow[t];
    float a128 = (float)((const _Float16*)xrow)[256];
    float b128 = (float)((const _Float16*)brow)[256];
    const unsigned int* xn = nullptr; const unsigned int* bn_ = nullptr; float cn = 0.f;
    if (it + 1 < end) resolve(it + 1, xn, bn_, cn);
    float axv=(float)a.h[0], ayv=(float)a.h[1], bxv=(float)b.h[0], byv=(float)b.h[1];
    ax_ += coef*(axv*bxv + ayv*byv);
    ay_ += coef*(axv*byv - ayv*bxv);
    ex  += coef*a128*b128;
    if (it + 1 < end){ xrow = xn; brow = bn_; coef = cn; }
  }
  unsigned int* orow = (unsigned int*)(AGGh + (size_t)node*288);
  HU o; o.h[0] = sat16(ax_); o.h[1] = sat16(ay_);
  orow[t] = o.u;
  if (t < 16){
    HU o2; o2.h[0] = (t == 0) ? sat16(ex) : (_Float16)0.f; o2.h[1] = (_Float16)0.f;
    orow[128 + t] = o2.u;
  }
}

__global__ void k_bnstats(const float* __restrict__ opre, float* __restrict__ bns){
  int col = threadIdx.x;
  int r0 = blockIdx.x*64, r1 = r0 + 64; if (r1 > NN) r1 = NN;
  float s1 = 0.f, s2 = 0.f;
  for (int r = r0; r < r1; ++r){
    float v = opre[(size_t)r*256 + col];
    s1 += v; s2 += v*v;
  }
  atomAddF(&bns[col], s1);
  atomAddF(&bns[256 + col], s2);
}

__global__ void k_bnfinal(float* __restrict__ bns, const float* __restrict__ gamma,
                          const float* __restrict__ beta){
  int col = threadIdx.x;
  float mean = bns[col] * (1.f/NN);
  float var  = bns[256 + col] * (1.f/NN) - mean*mean;
  var = fmaxf(var, 0.f);
  float g = gamma[col] * rsqrtf(var + 9e-5f);
  float b = beta[col] - mean*g;
  bns[512 + col] = sanit(g);
  bns[768 + col] = sanit(b);
}

__global__ void k_ent(const float* __restrict__ opre, const float* __restrict__ bns,
                      float* __restrict__ out){
  int t = blockIdx.x*256 + threadIdx.x;
  if (t >= NN*64) return;
  float4 v = ((const float4*)opre)[t];
  int col = (t & 63)*4;
  float g0 = bns[512+col],   b0 = bns[768+col];
  float g1 = bns[512+col+1], b1 = bns[768+col+1];
  float g2 = bns[512+col+2], b2 = bns[768+col+2];
  float g3 = bns[512+col+3], b3 = bns[768+col+3];
  float4 o;
  o.x = sanit(tanhf(v.x*g0 + b0));
  o.y = sanit(tanhf(v.y*g1 + b1));
  o.z = sanit(tanhf(v.z*g2 + b2));
  o.w = sanit(tanhf(v.w*g3 + b3));
  ((float4*)out)[t] = o;
}

__global__ void k_rel_out(const float* __restrict__ ral32, const float* __restrict__ w_rel,
                          float* __restrict__ out){
  int r = blockIdx.x, n = threadIdx.x;
  float acc = 0.f;
  for (int k = 0; k < 256; ++k)
    acc += ral32[r*256 + k] * w_rel[k*256 + n];
  out[12800000 + r*256 + n] = sanit(acc);
}

extern "C" void kernel_launch(void* const* d_in, const int* in_sizes, int n_in,
                              void* d_out, int out_size, void* d_ws, size_t ws_size,
                              hipStream_t stream){
  (void)in_sizes; (void)n_in;
  if (ws_size < WS_NEED){
    hipMemsetAsync(d_out, 0, (size_t)out_size*4, stream);
    return;
  }
  const float* x        = (const float*)d_in[0];
  const float* rel_emb  = (const float*)d_in[1];
  const float* w_in     = (const float*)d_in[2];
  const float* w_out_   = (const float*)d_in[3];
  const float* w_loop   = (const float*)d_in[4];
  const float* w_rel    = (const float*)d_in[5];
  const float* w_q      = (const float*)d_in[6];
  const float* loop_rel = (const float*)d_in[7];
  const float* gamma    = (const float*)d_in[9];
  const float* beta     = (const float*)d_in[10];
  const int* ei    = (const int*)d_in[11];
  const int* et    = (const int*)d_in[12];
  const int* quals = (const int*)d_in[13];
  float* out = (float*)d_out;
  char* W = (char*)d_ws;
  _Float16* xh    = (_Float16*)(W + O_XH);
  _Float16* AGGh  = (_Float16*)(W + O_XH);
  _Float16* Xhat  = (_Float16*)(W + O_XHAT);
  _Float16* Yhat  = (_Float16*)(W + O_YH);
  float*    opre  = (float*)(W + O_OPRE);
  _Float16* FR    = (_Float16*)(W + O_FR);
  _Float16* FI2   = (_Float16*)(W + O_FI2);
  _Float16* T1    = (_Float16*)(W + O_T1);
  _Float16* G     = (_Float16*)(W + O_G);
  _Float16* WB    = (_Float16*)(W + O_WB);
  _Float16* wqn   = (_Float16*)(W + O_WQN);
  _Float16* wint  = (_Float16*)(W + O_WINT);
  _Float16* woutt = (_Float16*)(W + O_WOUT);
  _Float16* ral16 = (_Float16*)(W + O_RAL16);
  float*    ral32 = (float*)(W + O_RAL32);
  _Float16* Rhat  = (_Float16*)(W + O_RHAT);
  int*      deg   = (int*)(W + O_DEG);
  float*    dinv  = (float*)(W + O_DINV);
  float*    bns   = (float*)(W + O_BNS);
  int*      cnt   = (int*)(W + O_CNT);
  int*      ptr   = (int*)(W + O_PTR);
  int*      cur   = (int*)(W + O_CUR);
  int*      bsum  = (int*)(W + O_BSUM);
  int*      items = (int*)(W + O_ITEMS);

  hipMemsetAsync(deg, 0, 400000, stream);
  hipMemsetAsync(cnt, 0, 400000, stream);
  hipMemsetAsync(bns, 0, 4096, stream);

  k_gen_dft <<<288, 256, 0, stream>>>(FR, FI2);
  k_gen_misc<<<501, 256, 0, stream>>>(w_in, w_out_, w_q, rel_emb, loop_rel,
                                      wqn, wint, woutt, ral32, ral16);
  k_gen_bw  <<<256, 256, 0, stream>>>(loop_rel, w_loop, WB);
  k_cvt_x   <<<6250, 256, 0, stream>>>(x, xh, 1600000);
  k_deg     <<<2344, 256, 0, stream>>>(ei, deg);
  k_dinv    <<<391, 256, 0, stream>>>(deg, dinv);

  // unified CSR (both directions), hierarchical scan
  k_cnt  <<<3125, 256, 0, stream>>>(ei, quals, cnt);
  k_scan1<<<SCB, 256, 0, stream>>>(cnt, bsum);
  k_scan2<<<1, 64, 0, stream>>>(bsum, ptr);
  k_scan3<<<SCB, 256, 0, stream>>>(cnt, bsum, ptr);
  hipMemcpyAsync(cur, ptr, 400000, hipMemcpyDeviceToDevice, stream);
  k_fill <<<3125, 256, 0, stream>>>(ei, quals, cur, items);

  // T1 = FR @ wqn^T ; G = T1 @ FI2^T   (G = Fr.Wq^T.Fi^T)
  k_gemm<_Float16,false><<<dim3(3,2), 256, 0, stream>>>(FR, 256, wqn, 256, T1, 256, 256, 256);
  k_gemm<_Float16,false><<<dim3(3,3), 256, 0, stream>>>(T1, 256, FI2, 256, G, 288, 288, 256);
  // WB[:,0:288] = (Fi.W_in)^T-pack ; WB[:,288:576] for w_out
  k_gemm<_Float16,false><<<dim3(2,3), 256, 0, stream>>>(wint, 256, FI2, 256, WB, 832, 288, 256);
  k_gemm<_Float16,false><<<dim3(2,3), 256, 0, stream>>>(woutt, 256, FI2, 256, WB + 288, 832, 288, 256);

  // Xhat = x @ FR^T ; Rhat = rel_all @ FR^T
  k_gemm<_Float16,false><<<dim3(391,3), 256, 0, stream>>>(xh, 256, FR, 256, Xhat, 288, 288, 256);
  k_gemm<_Float16,false><<<dim3(4,3),  256, 0, stream>>>(ral16, 256, FR, 256, Rhat, 288, 288, 256);

  // opre = x @ BW (self-loop)
  k_gemm<float,false><<<dim3(391,2), 256, 0, stream>>>(xh, 256, WB + 576, 832, opre, 256, 256, 256);

  for (int d = 0; d < 2; ++d){
    k_qgemm<<<dim3(782,3), 256, 0, stream>>>(Xhat, Rhat, quals, d, G, Yhat);
    k_agg<<<NN, 128, 0, stream>>>(Xhat, Rhat, Yhat, ptr, items, ei, et, quals, dinv, d, AGGh);
    k_gemm<float,true><<<dim3(391,2), 256, 0, stream>>>(AGGh, 288, WB + (size_t)d*288, 832,
                                                        opre, 256, 256, 288);
  }

  k_bnstats<<<782, 256, 0, stream>>>(opre, bns);
  k_bnfinal<<<1, 256, 0, stream>>>(bns, gamma, beta);
  k_ent<<<12500, 256, 0, stream>>>(opre, bns, out);
  k_rel_out<<<500, 256, 0, stream>>>(ral32, w_rel, out);
}

// Round 8
// 692.235 us; speedup vs baseline: 3.1347x; 1.1492x over previous
//
#include <hip/hip_runtime.h>

typedef __attribute__((ext_vector_type(8))) _Float16 f16x8;
typedef __attribute__((ext_vector_type(4))) float f32x4;

#define NN   50000
#define EE   300000
#define TWOE 600000
#define TWOQ 200000
#define SCB  98     // scan blocks of 1024 ints covering 2*NN=100000

// ---- workspace layout (bytes), total 184,064,704 (<= proven 184,089,664) ----
static constexpr size_t O_XH   = 0;            // xh f16 [50048,256]; AGGh f16 [50048,288] aliases
static constexpr size_t O_XHAT = 28827648;     // f16 [50048,288]
static constexpr size_t O_YH   = 57655296;     // f16 [100096,288] per-direction Yhat
static constexpr size_t O_OPRE = 115310592;    // f16 [50048,256]
static constexpr size_t O_FR   = 166559744;    // f16 [384,256]
static constexpr size_t O_FI2  = O_FR   + 196608;   // f16 [384,256]
static constexpr size_t O_T1   = O_FI2  + 196608;   // f16 [384,256]
static constexpr size_t O_G    = O_T1   + 196608;   // f16 [384,288]
static constexpr size_t O_WB   = O_G    + 221184;   // f16 [256,832]
static constexpr size_t O_WQN  = O_WB   + 425984;   // f16 [256,256]
static constexpr size_t O_WINT = O_WQN  + 131072;   // f16 [256,256]
static constexpr size_t O_WOUT = O_WINT + 131072;   // f16 [256,256]
static constexpr size_t O_RAL16= O_WOUT + 131072;   // f16 [512,256]
static constexpr size_t O_RAL32= O_RAL16+ 262144;   // f32 [501,256]
static constexpr size_t O_RHAT = O_RAL32+ 513024;   // f16 [512,288]
static constexpr size_t O_DEG  = O_RHAT + 294912;   // int [2,N]
static constexpr size_t O_DINV = O_DEG  + 400000;   // f32 [2,N]
static constexpr size_t O_BNS  = O_DINV + 400000;   // f32 [1024]
static constexpr size_t O_CNT  = O_BNS  + 4096;     // int [2N]
static constexpr size_t O_PTR  = O_CNT  + 400000;   // int [2N+1]
static constexpr size_t O_CUR  = O_PTR  + 400064;   // int [2N]
static constexpr size_t O_BSUM = O_CUR  + 400000;   // int [128]
static constexpr size_t O_RECS = O_BSUM + 512;      // int4 [800000] = 12.8MB
static constexpr size_t WS_NEED= O_RECS + 12800000;

__device__ __forceinline__ float sanit(float v){
  v = (v == v) ? v : 0.f;
  return fminf(60000.f, fmaxf(-60000.f, v));
}
__device__ __forceinline__ _Float16 sat16(float v){ return (_Float16)sanit(v); }
__device__ __forceinline__ int iclamp(int v, int lo, int hi){
  return v < lo ? lo : (v > hi ? hi : v);
}
__device__ __forceinline__ void atomAddF(float* p, float v){
  __hip_atomic_fetch_add(p, v, __ATOMIC_RELAXED, __HIP_MEMORY_SCOPE_AGENT);
}
union HU { unsigned int u; _Float16 h[2]; };

__device__ __forceinline__ unsigned int cmulh(unsigned int ua, unsigned int ub){
  HU a, b, o; a.u = ua; b.u = ub;
  float ax=(float)a.h[0], ay=(float)a.h[1], bx=(float)b.h[0], by=(float)b.h[1];
  o.h[0] = (_Float16)(ax*bx + ay*by);
  o.h[1] = (_Float16)(ax*by - ay*bx);
  return o.u;
}

// ---- fused prologue: block-range dispatch over 6 independent jobs ----
// [0,288) gen_dft | [288,789) gen_misc | [789,1045) gen_bw | [1045,7295) cvt_x
// [7295,9639) deg | [9639,12764) cnt
__global__ void k_pro(_Float16* __restrict__ FR, _Float16* __restrict__ FI2,
                      const float* __restrict__ w_in, const float* __restrict__ w_out,
                      const float* __restrict__ w_q, const float* __restrict__ rel_embed,
                      const float* __restrict__ loop_rel, const float* __restrict__ w_loop,
                      _Float16* __restrict__ wqn, _Float16* __restrict__ wint,
                      _Float16* __restrict__ woutt,
                      float* __restrict__ ral32, _Float16* __restrict__ ral16,
                      _Float16* __restrict__ WB,
                      const float* __restrict__ x, _Float16* __restrict__ xh,
                      const int* __restrict__ ei, const int* __restrict__ quals,
                      int* __restrict__ deg, int* __restrict__ cnt){
  int b = blockIdx.x, tid = threadIdx.x;
  if (b < 288){
    int t = b*256 + tid;
    const float step = 0.024543692606170259f; // 2*pi/256
    {
      int f = t >> 8, tt = t & 255;
      float v = 0.f;
      if (f < 258){
        int m = f >> 1;
        float ang = (float)((tt*m) & 255) * step;
        v = (f & 1) ? -sinf(ang) : cosf(ang);
      }
      FR[t] = (_Float16)v;
    }
    {
      int k = t >> 8, j = t & 255;
      float v = 0.f;
      if (k < 258){
        int m = k >> 1;
        float w = (m==0 || m==128) ? (1.f/256.f) : (2.f/256.f);
        float ang = (float)((j*m) & 255) * step;
        v = (k & 1) ? -w*sinf(ang) : w*cosf(ang);
      }
      FI2[t] = (_Float16)v;
    }
  } else if (b < 789){
    int t = (b - 288)*256 + tid;
    if (t < 65536){
      int j = t >> 8, n = t & 255;
      wqn[t] = sat16(w_q[t]);
      wint[n*256 + j]  = sat16(w_in[t]);
      woutt[n*256 + j] = sat16(w_out[t]);
    }
    if (t < 128256){
      float rv = (t < 128000) ? rel_embed[t] : loop_rel[t - 128000];
      rv = sanit(rv);
      ral32[t] = rv; ral16[t] = (_Float16)rv;
    }
  } else if (b < 1045){
    int t = (b - 789)*256 + tid;   // < 65536
    int j = t >> 8, n = t & 255;
    float acc = 0.f;
    for (int m = 0; m < 256; ++m)
      acc += loop_rel[(j+m) & 255] * w_loop[m*256 + n];
    WB[n*832 + 576 + j] = sat16(acc);
  } else if (b < 7295){
    int t = (b - 1045)*256 + tid;  // < 1,600,000 exactly
    const float4* p = (const float4*)x + (size_t)t*2;
    float4 v0 = p[0], v1 = p[1];
    f16x8 o;
    o[0]=sat16(v0.x); o[1]=sat16(v0.y); o[2]=sat16(v0.z); o[3]=sat16(v0.w);
    o[4]=sat16(v1.x); o[5]=sat16(v1.y); o[6]=sat16(v1.z); o[7]=sat16(v1.w);
    ((f16x8*)xh)[t] = o;
  } else if (b < 9639){
    int t = (b - 7295)*256 + tid;
    if (t < TWOE){
      int d = (t >= EE) ? 1 : 0;
      atomicAdd(&deg[d*NN + iclamp(ei[t], 0, NN-1)], 1);
    }
  } else {
    int t = (b - 9639)*256 + tid;  // < 800,000 exactly
    if (t < TWOE){
      int d = (t >= EE) ? 1 : 0;
      atomicAdd(&cnt[d*NN + iclamp(ei[TWOE + t], 0, NN-1)], 1);
    } else {
      int qg = t - TWOE;
      int d = (qg >= 100000) ? 1 : 0;
      int e = iclamp(quals[2*TWOQ + qg], 0, EE-1);
      int j = d*EE + e;
      atomicAdd(&cnt[d*NN + iclamp(ei[TWOE + j], 0, NN-1)], 1);
    }
  }
}

__global__ void k_dinv(const int* __restrict__ deg, float* __restrict__ dinv){
  int t = blockIdx.x*256 + threadIdx.x;
  if (t >= 2*NN) return;
  int c = deg[t];
  dinv[t] = (c > 0) ? rsqrtf((float)c) : 0.f;
}

// hierarchical exclusive scan of cnt[0..2N) -> ptr[0..2N] (+cur copy)
__global__ void k_scan1(const int* __restrict__ cnt, int* __restrict__ bsum){
  __shared__ int sh[256];
  int b = blockIdx.x, t = threadIdx.x;
  int base = b*1024 + t*4;
  int s = 0;
  #pragma unroll
  for (int i = 0; i < 4; ++i){ int idx = base + i; if (idx < 2*NN) s += cnt[idx]; }
  sh[t] = s; __syncthreads();
  for (int off = 128; off > 0; off >>= 1){
    if (t < off) sh[t] += sh[t + off];
    __syncthreads();
  }
  if (t == 0) bsum[b] = sh[0];
}

__global__ void k_scan2(int* __restrict__ bsum, int* __restrict__ ptr){
  if (threadIdx.x == 0){
    int run = 0;
    for (int i = 0; i < SCB; ++i){ int v = bsum[i]; bsum[i] = run; run += v; }
    ptr[2*NN] = run;
  }
}

__global__ void k_scan3(const int* __restrict__ cnt, const int* __restrict__ bsum,
                        int* __restrict__ ptr, int* __restrict__ cur){
  __shared__ int sh[256];
  int b = blockIdx.x, t = threadIdx.x;
  int base = b*1024 + t*4;
  int v[4];
  int s = 0;
  #pragma unroll
  for (int i = 0; i < 4; ++i){
    int idx = base + i;
    v[i] = (idx < 2*NN) ? cnt[idx] : 0;
    s += v[i];
  }
  sh[t] = s; __syncthreads();
  for (int off = 1; off < 256; off <<= 1){
    int add = (t >= off) ? sh[t - off] : 0;
    __syncthreads();
    sh[t] += add;
    __syncthreads();
  }
  int off0 = bsum[b] + sh[t] - s;
  #pragma unroll
  for (int i = 0; i < 4; ++i){
    int idx = base + i;
    if (idx < 2*NN){ ptr[idx] = off0; cur[idx] = off0; }
    off0 += v[i];
  }
}

// per-item records: {xhat_byte_off, b_byte_off, coef_bits, 0}
__global__ void k_fillrec(const int* __restrict__ ei, const int* __restrict__ et,
                          const int* __restrict__ quals, const float* __restrict__ dinv,
                          int* __restrict__ cursor, int4* __restrict__ recs){
  int t = blockIdx.x*256 + threadIdx.x;
  if (t >= TWOE + TWOQ) return;
  int d, j, boff; float w;
  if (t < TWOE){
    d = (t >= EE) ? 1 : 0;
    j = t;
    boff = (int)O_RHAT + iclamp(et[j], 0, 500)*576;
    w = 0.8f;
  } else {
    int qg = t - TWOE;
    d = (qg >= 100000) ? 1 : 0;
    int e = iclamp(quals[2*TWOQ + qg], 0, EE-1);
    j = d*EE + e;
    boff = (int)O_YH + (qg - d*100000)*576;
    w = 0.2f;
  }
  int src = iclamp(ei[j], 0, NN-1);
  int dst = iclamp(ei[TWOE + j], 0, NN-1);
  float coef = w * dinv[d*NN + src] * dinv[d*NN + dst];
  int pos = atomicAdd(&cursor[d*NN + dst], 1);
  pos = iclamp(pos, 0, 800000-1);
  int4 rc;
  rc.x = (int)O_XHAT + src*576;
  rc.y = boff;
  rc.z = __float_as_int(coef);
  rc.w = 0;
  recs[pos] = rc;
}

// C[M,N](ldc) = A[.,K](lda) @ Bt[.,K](ldb)^T; fp32 accum; UNGUARDED loads
// (A rows padded to gridDim.x*128, Bt rows padded to gridDim.y*128, K%32==0).
template<typename OT, bool ACC>
__global__ __launch_bounds__(256) void k_gemm(const _Float16* __restrict__ A, int lda,
                                              const _Float16* __restrict__ Bt, int ldb,
                                              OT* __restrict__ C, int ldc,
                                              int N, int K){
  __shared__ _Float16 Ash[128*40];
  __shared__ _Float16 Bsh[128*40];
  const int tid = threadIdx.x;
  const int lane = tid & 63;
  const int wv = tid >> 6;
  const int bm = blockIdx.x*128, bn = blockIdx.y*128;
  const int wm = (wv >> 1)*64, wn = (wv & 1)*64;
  const int sr = tid >> 1;
  const int sc = (tid & 1)*16;
  const int fr = lane & 15;
  const int fk = (lane >> 4)*8;
  const _Float16* pa = A + (size_t)(bm+sr)*lda + sc;
  const _Float16* pb = Bt + (size_t)(bn+sr)*ldb + sc;
  f32x4 acc[4][4] = {};
  for (int kt = 0; kt < K; kt += 32){
    float4 a0 = *(const float4*)(pa);
    float4 a1 = *(const float4*)(pa + 8);
    float4 b0 = *(const float4*)(pb);
    float4 b1 = *(const float4*)(pb + 8);
    pa += 32; pb += 32;
    __syncthreads();
    *(float4*)&Ash[sr*40 + sc]     = a0;
    *(float4*)&Ash[sr*40 + sc + 8] = a1;
    *(float4*)&Bsh[sr*40 + sc]     = b0;
    *(float4*)&Bsh[sr*40 + sc + 8] = b1;
    __syncthreads();
    f16x8 af[4], bf_[4];
    #pragma unroll
    for (int i = 0; i < 4; ++i) af[i]  = *(const f16x8*)&Ash[(wm + i*16 + fr)*40 + fk];
    #pragma unroll
    for (int j = 0; j < 4; ++j) bf_[j] = *(const f16x8*)&Bsh[(wn + j*16 + fr)*40 + fk];
    #pragma unroll
    for (int i = 0; i < 4; ++i)
      #pragma unroll
      for (int j = 0; j < 4; ++j)
        acc[i][j] = __builtin_amdgcn_mfma_f32_16x16x32_f16(af[i], bf_[j], acc[i][j], 0, 0, 0);
  }
  const int cr = (lane >> 4)*4;
  const int cc = lane & 15;
  #pragma unroll
  for (int i = 0; i < 4; ++i)
    #pragma unroll
    for (int j = 0; j < 4; ++j){
      int col = bn + wn + j*16 + cc;
      if (col < N){
        #pragma unroll
        for (int r = 0; r < 4; ++r){
          size_t idx = (size_t)(bm + wm + i*16 + cr + r)*ldc + col;
          float v = acc[i][j][r];
          if (ACC) v += (float)C[idx];
          C[idx] = (OT)sanit(v);
        }
      }
    }
}

// Fused qual GEMM: Yhat[q] = (conj(Xhat[ent_q]) .* Rhat[rel_q]) @ G^T
__global__ __launch_bounds__(256) void k_qgemm(const _Float16* __restrict__ Xhat,
                                               const _Float16* __restrict__ Rhat,
                                               const int* __restrict__ quals, int d,
                                               const _Float16* __restrict__ G,
                                               _Float16* __restrict__ Yhat){
  __shared__ _Float16 Ash[128*40];
  __shared__ _Float16 Bsh[128*40];
  const int tid = threadIdx.x;
  const int lane = tid & 63;
  const int wv = tid >> 6;
  const int bm = blockIdx.x*128, bn = blockIdx.y*128;
  const int wm = (wv >> 1)*64, wn = (wv & 1)*64;
  const int sr = tid >> 1;
  const int h  = tid & 1;
  const int fr = lane & 15;
  const int fk = (lane >> 4)*8;
  int q = bm + sr; if (q > 99999) q = 99999;
  int qi = d*100000 + q;
  int rel = iclamp(quals[qi], 0, 500);
  int ent = iclamp(quals[TWOQ + qi], 0, NN-1);
  const unsigned int* xr = (const unsigned int*)(Xhat + (size_t)ent*288);
  const unsigned int* rr = (const unsigned int*)(Rhat + (size_t)rel*288);
  const _Float16* pb = G + (size_t)(bn+sr)*288 + h*16;
  f32x4 acc[4][4] = {};
  for (int kt = 0; kt < 288; kt += 32){
    int kb = (kt >> 1) + h*8;
    uint4 xa0 = *(const uint4*)(xr + kb);
    uint4 xa1 = *(const uint4*)(xr + kb + 4);
    uint4 ra0 = *(const uint4*)(rr + kb);
    uint4 ra1 = *(const uint4*)(rr + kb + 4);
    float4 b0 = *(const float4*)(pb);
    float4 b1 = *(const float4*)(pb + 8);
    pb += 32;
    uint4 oa0, oa1;
    oa0.x = cmulh(xa0.x, ra0.x); oa0.y = cmulh(xa0.y, ra0.y);
    oa0.z = cmulh(xa0.z, ra0.z); oa0.w = cmulh(xa0.w, ra0.w);
    oa1.x = cmulh(xa1.x, ra1.x); oa1.y = cmulh(xa1.y, ra1.y);
    oa1.z = cmulh(xa1.z, ra1.z); oa1.w = cmulh(xa1.w, ra1.w);
    __syncthreads();
    *(uint4*)&Ash[sr*40 + h*16]     = oa0;
    *(uint4*)&Ash[sr*40 + h*16 + 8] = oa1;
    *(float4*)&Bsh[sr*40 + h*16]     = b0;
    *(float4*)&Bsh[sr*40 + h*16 + 8] = b1;
    __syncthreads();
    f16x8 af[4], bf_[4];
    #pragma unroll
    for (int i = 0; i < 4; ++i) af[i]  = *(const f16x8*)&Ash[(wm + i*16 + fr)*40 + fk];
    #pragma unroll
    for (int j = 0; j < 4; ++j) bf_[j] = *(const f16x8*)&Bsh[(wn + j*16 + fr)*40 + fk];
    #pragma unroll
    for (int i = 0; i < 4; ++i)
      #pragma unroll
      for (int j = 0; j < 4; ++j)
        acc[i][j] = __builtin_amdgcn_mfma_f32_16x16x32_f16(af[i], bf_[j], acc[i][j], 0, 0, 0);
  }
  const int cr = (lane >> 4)*4;
  const int cc = lane & 15;
  #pragma unroll
  for (int i = 0; i < 4; ++i)
    #pragma unroll
    for (int j = 0; j < 4; ++j){
      int col = bn + wn + j*16 + cc;
      if (col < 288){
        #pragma unroll
        for (int r = 0; r < 4; ++r){
          size_t idx = (size_t)(bm + wm + i*16 + cr + r)*288 + col;
          Yhat[idx] = sat16(acc[i][j][r]);
        }
      }
    }
}

// ---- gather-aggregate via records, 1-deep data prefetch ----
__global__ __launch_bounds__(128) void k_agg(const char* Wb,
                                             const int* ptr,
                                             const int4* recs,
                                             int d, _Float16* AGGh){
  int node = blockIdx.x;
  int t = threadIdx.x;
  int gnode = d*NN + node;
  int beg = ptr[gnode], end = ptr[gnode+1];
  float ax_ = 0.f, ay_ = 0.f, ex = 0.f;
  int4 rc; unsigned int va = 0, vb = 0; float a128 = 0.f, b128 = 0.f;
  if (beg < end){
    rc = recs[beg];
    const unsigned int* xr = (const unsigned int*)(Wb + rc.x);
    const unsigned int* br = (const unsigned int*)(Wb + rc.y);
    va = xr[t]; vb = br[t];
    a128 = (float)((const _Float16*)xr)[256];
    b128 = (float)((const _Float16*)br)[256];
  }
  for (int it = beg; it < end; ++it){
    int4 rn = rc; unsigned int van = 0, vbn = 0; float an = 0.f, bn2 = 0.f;
    if (it + 1 < end){
      rn = recs[it + 1];
      const unsigned int* xr = (const unsigned int*)(Wb + rn.x);
      const unsigned int* br = (const unsigned int*)(Wb + rn.y);
      van = xr[t]; vbn = br[t];
      an = (float)((const _Float16*)xr)[256];
      bn2 = (float)((const _Float16*)br)[256];
    }
    float coef = __int_as_float(rc.z);
    HU a, b; a.u = va; b.u = vb;
    float axv=(float)a.h[0], ayv=(float)a.h[1], bxv=(float)b.h[0], byv=(float)b.h[1];
    ax_ += coef*(axv*bxv + ayv*byv);
    ay_ += coef*(axv*byv - ayv*bxv);
    ex  += coef*a128*b128;
    rc = rn; va = van; vb = vbn; a128 = an; b128 = bn2;
  }
  unsigned int* orow = (unsigned int*)(AGGh + (size_t)node*288);
  HU o; o.h[0] = sat16(ax_); o.h[1] = sat16(ay_);
  orow[t] = o.u;
  if (t < 16){
    HU o2; o2.h[0] = (t == 0) ? sat16(ex) : (_Float16)0.f; o2.h[1] = (_Float16)0.f;
    orow[128 + t] = o2.u;
  }
}

__global__ void k_bnstats(const _Float16* __restrict__ opre, float* __restrict__ bns){
  int col = threadIdx.x;
  int r0 = blockIdx.x*64, r1 = r0 + 64; if (r1 > NN) r1 = NN;
  float s1 = 0.f, s2 = 0.f;
  for (int r = r0; r < r1; ++r){
    float v = (float)opre[(size_t)r*256 + col];
    s1 += v; s2 += v*v;
  }
  atomAddF(&bns[col], s1);
  atomAddF(&bns[256 + col], s2);
}

__global__ void k_bnfinal(float* __restrict__ bns, const float* __restrict__ gamma,
                          const float* __restrict__ beta){
  int col = threadIdx.x;
  float mean = bns[col] * (1.f/NN);
  float var  = bns[256 + col] * (1.f/NN) - mean*mean;
  var = fmaxf(var, 0.f);
  // BN of (acc/3 + bias) == (acc-mean_acc)/sqrt(var_acc + 9*eps); bias cancels
  float g = gamma[col] * rsqrtf(var + 9e-5f);
  float b = beta[col] - mean*g;
  bns[512 + col] = sanit(g);
  bns[768 + col] = sanit(b);
}

__global__ void k_ent(const _Float16* __restrict__ opre, const float* __restrict__ bns,
                      float* __restrict__ out){
  int t = blockIdx.x*256 + threadIdx.x;
  if (t >= NN*32) return;
  f16x8 v = ((const f16x8*)opre)[t];
  int col = (t & 31)*8;
  float4 o0, o1;
  o0.x = sanit(tanhf((float)v[0]*bns[512+col+0] + bns[768+col+0]));
  o0.y = sanit(tanhf((float)v[1]*bns[512+col+1] + bns[768+col+1]));
  o0.z = sanit(tanhf((float)v[2]*bns[512+col+2] + bns[768+col+2]));
  o0.w = sanit(tanhf((float)v[3]*bns[512+col+3] + bns[768+col+3]));
  o1.x = sanit(tanhf((float)v[4]*bns[512+col+4] + bns[768+col+4]));
  o1.y = sanit(tanhf((float)v[5]*bns[512+col+5] + bns[768+col+5]));
  o1.z = sanit(tanhf((float)v[6]*bns[512+col+6] + bns[768+col+6]));
  o1.w = sanit(tanhf((float)v[7]*bns[512+col+7] + bns[768+col+7]));
  ((float4*)out)[(size_t)t*2]     = o0;
  ((float4*)out)[(size_t)t*2 + 1] = o1;
}

__global__ void k_rel_out(const float* __restrict__ ral32, const float* __restrict__ w_rel,
                          float* __restrict__ out){
  int r = blockIdx.x, n = threadIdx.x;
  float acc = 0.f;
  for (int k = 0; k < 256; ++k)
    acc += ral32[r*256 + k] * w_rel[k*256 + n];
  out[12800000 + r*256 + n] = sanit(acc);
}

extern "C" void kernel_launch(void* const* d_in, const int* in_sizes, int n_in,
                              void* d_out, int out_size, void* d_ws, size_t ws_size,
                              hipStream_t stream){
  (void)in_sizes; (void)n_in;
  if (ws_size < WS_NEED){
    hipMemsetAsync(d_out, 0, (size_t)out_size*4, stream);
    return;
  }
  const float* x        = (const float*)d_in[0];
  const float* rel_emb  = (const float*)d_in[1];
  const float* w_in     = (const float*)d_in[2];
  const float* w_out_   = (const float*)d_in[3];
  const float* w_loop   = (const float*)d_in[4];
  const float* w_rel    = (const float*)d_in[5];
  const float* w_q      = (const float*)d_in[6];
  const float* loop_rel = (const float*)d_in[7];
  const float* gamma    = (const float*)d_in[9];
  const float* beta     = (const float*)d_in[10];
  const int* ei    = (const int*)d_in[11];
  const int* et    = (const int*)d_in[12];
  const int* quals = (const int*)d_in[13];
  float* out = (float*)d_out;
  char* W = (char*)d_ws;
  _Float16* xh    = (_Float16*)(W + O_XH);
  _Float16* AGGh  = (_Float16*)(W + O_XH);
  _Float16* Xhat  = (_Float16*)(W + O_XHAT);
  _Float16* Yhat  = (_Float16*)(W + O_YH);
  _Float16* opre  = (_Float16*)(W + O_OPRE);
  _Float16* FR    = (_Float16*)(W + O_FR);
  _Float16* FI2   = (_Float16*)(W + O_FI2);
  _Float16* T1    = (_Float16*)(W + O_T1);
  _Float16* G     = (_Float16*)(W + O_G);
  _Float16* WB    = (_Float16*)(W + O_WB);
  _Float16* wqn   = (_Float16*)(W + O_WQN);
  _Float16* wint  = (_Float16*)(W + O_WINT);
  _Float16* woutt = (_Float16*)(W + O_WOUT);
  _Float16* ral16 = (_Float16*)(W + O_RAL16);
  float*    ral32 = (float*)(W + O_RAL32);
  _Float16* Rhat  = (_Float16*)(W + O_RHAT);
  int*      deg   = (int*)(W + O_DEG);
  float*    dinv  = (float*)(W + O_DINV);
  float*    bns   = (float*)(W + O_BNS);
  int*      cnt   = (int*)(W + O_CNT);
  int*      ptr   = (int*)(W + O_PTR);
  int*      cur   = (int*)(W + O_CUR);
  int*      bsum  = (int*)(W + O_BSUM);
  int4*     recs  = (int4*)(W + O_RECS);

  hipMemsetAsync(deg, 0, 400000, stream);
  hipMemsetAsync(cnt, 0, 400000, stream);
  hipMemsetAsync(bns, 0, 4096, stream);

  k_pro<<<12764, 256, 0, stream>>>(FR, FI2, w_in, w_out_, w_q, rel_emb, loop_rel, w_loop,
                                   wqn, wint, woutt, ral32, ral16, WB, x, xh,
                                   ei, quals, deg, cnt);
  k_dinv <<<391, 256, 0, stream>>>(deg, dinv);
  k_scan1<<<SCB, 256, 0, stream>>>(cnt, bsum);
  k_scan2<<<1, 64, 0, stream>>>(bsum, ptr);
  k_scan3<<<SCB, 256, 0, stream>>>(cnt, bsum, ptr, cur);
  k_fillrec<<<3125, 256, 0, stream>>>(ei, et, quals, dinv, cur, recs);

  // T1 = FR @ wqn^T ; G = T1 @ FI2^T   (G = Fr.Wq^T.Fi^T)
  k_gemm<_Float16,false><<<dim3(3,2), 256, 0, stream>>>(FR, 256, wqn, 256, T1, 256, 256, 256);
  k_gemm<_Float16,false><<<dim3(3,3), 256, 0, stream>>>(T1, 256, FI2, 256, G, 288, 288, 256);
  // WB[:,0:288] = (Fi.W_in)^T-pack ; WB[:,288:576] for w_out
  k_gemm<_Float16,false><<<dim3(2,3), 256, 0, stream>>>(wint, 256, FI2, 256, WB, 832, 288, 256);
  k_gemm<_Float16,false><<<dim3(2,3), 256, 0, stream>>>(woutt, 256, FI2, 256, WB + 288, 832, 288, 256);

  // Xhat = x @ FR^T ; Rhat = rel_all @ FR^T
  k_gemm<_Float16,false><<<dim3(391,3), 256, 0, stream>>>(xh, 256, FR, 256, Xhat, 288, 288, 256);
  k_gemm<_Float16,false><<<dim3(4,3),  256, 0, stream>>>(ral16, 256, FR, 256, Rhat, 288, 288, 256);

  // opre = x @ BW (self-loop); f16 output
  k_gemm<_Float16,false><<<dim3(391,2), 256, 0, stream>>>(xh, 256, WB + 576, 832, opre, 256, 256, 256);

  for (int d = 0; d < 2; ++d){
    k_qgemm<<<dim3(782,3), 256, 0, stream>>>(Xhat, Rhat, quals, d, G, Yhat);
    k_agg<<<NN, 128, 0, stream>>>(W, ptr, recs, d, AGGh);
    k_gemm<_Float16,true><<<dim3(391,2), 256, 0, stream>>>(AGGh, 288, WB + (size_t)d*288, 832,
                                                           opre, 256, 256, 288);
  }

  k_bnstats<<<782, 256, 0, stream>>>(opre, bns);
  k_bnfinal<<<1, 256, 0, stream>>>(bns, gamma, beta);
  k_ent<<<6250, 256, 0, stream>>>(opre, bns, out);
  k_rel_out<<<500, 256, 0, stream>>>(ral32, w_rel, out);
}